// Round 1
// baseline (1435.904 us; speedup 1.0000x reference)
//
#include <hip/hip_runtime.h>
#include <hip/hip_bf16.h>

#define H 8
#define D 128
#define DIM 1024
#define QB 16
#define NSEQ 512
#define R (QB * NSEQ)      /* 8192 rows */
#define HR (H * R)         /* 65536 (h,row) pairs */

// ---------------------------------------------------------------------------
// LayerNorm over DIM=1024, one block (256 thr) per row, biased var, eps=1e-5
// ---------------------------------------------------------------------------
__global__ __launch_bounds__(256) void ln_kernel(const float* __restrict__ x,
                                                 const float* __restrict__ g,
                                                 const float* __restrict__ b,
                                                 float* __restrict__ out) {
    int r = blockIdx.x;
    int tid = threadIdx.x;
    const float* row = x + (size_t)r * DIM;
    float4 v = *(const float4*)(row + tid * 4);
    float sum = v.x + v.y + v.z + v.w;
    float sq = v.x * v.x + v.y * v.y + v.z * v.z + v.w * v.w;
    __shared__ float s1[256], s2[256];
    s1[tid] = sum; s2[tid] = sq;
    __syncthreads();
    for (int s = 128; s > 0; s >>= 1) {
        if (tid < s) { s1[tid] += s1[tid + s]; s2[tid] += s2[tid + s]; }
        __syncthreads();
    }
    float mean = s1[0] * (1.0f / DIM);
    float var = s2[0] * (1.0f / DIM) - mean * mean;
    float rstd = rsqrtf(var + 1e-5f);
    float4 gv = *(const float4*)(g + tid * 4);
    float4 bv = *(const float4*)(b + tid * 4);
    float4 o;
    o.x = (v.x - mean) * rstd * gv.x + bv.x;
    o.y = (v.y - mean) * rstd * gv.y + bv.y;
    o.z = (v.z - mean) * rstd * gv.z + bv.z;
    o.w = (v.w - mean) * rstd * gv.w + bv.w;
    *(float4*)(out + (size_t)r * DIM + tid * 4) = o;
}

// ---------------------------------------------------------------------------
// C[M,N] = A[M,K] @ B[N,K]^T (+ bias[n]); fp32, 64x64 tile, BK=16, 4x4/thread
// ---------------------------------------------------------------------------
template <int BIAS>
__global__ __launch_bounds__(256) void gemm_nt(const float* __restrict__ A,
                                               const float* __restrict__ B,
                                               const float* __restrict__ bias,
                                               float* __restrict__ C,
                                               int M, int N, int K) {
    __shared__ float As[16][68];
    __shared__ float Bs[16][68];
    int tid = threadIdx.x;
    int tx = tid & 15, ty = tid >> 4;
    int tx4 = tx * 4, ty4 = ty * 4;
    int m0 = blockIdx.y * 64, n0 = blockIdx.x * 64;
    int lrow = tid >> 2;          // 0..63
    int lcol = (tid & 3) * 4;     // 0,4,8,12
    float acc[4][4] = {};
    for (int kt = 0; kt < K; kt += 16) {
        float4 av = *(const float4*)(A + (size_t)(m0 + lrow) * K + kt + lcol);
        float4 bv = *(const float4*)(B + (size_t)(n0 + lrow) * K + kt + lcol);
        As[lcol + 0][lrow] = av.x; As[lcol + 1][lrow] = av.y;
        As[lcol + 2][lrow] = av.z; As[lcol + 3][lrow] = av.w;
        Bs[lcol + 0][lrow] = bv.x; Bs[lcol + 1][lrow] = bv.y;
        Bs[lcol + 2][lrow] = bv.z; Bs[lcol + 3][lrow] = bv.w;
        __syncthreads();
#pragma unroll
        for (int kk = 0; kk < 16; kk++) {
            float4 a4 = *(const float4*)&As[kk][ty4];
            float4 b4 = *(const float4*)&Bs[kk][tx4];
            float a_[4] = {a4.x, a4.y, a4.z, a4.w};
            float b_[4] = {b4.x, b4.y, b4.z, b4.w};
#pragma unroll
            for (int i = 0; i < 4; i++)
#pragma unroll
                for (int j = 0; j < 4; j++)
                    acc[i][j] = fmaf(a_[i], b_[j], acc[i][j]);
        }
        __syncthreads();
    }
#pragma unroll
    for (int i = 0; i < 4; i++) {
        int row = m0 + ty4 + i;
        float4 o = {acc[i][0], acc[i][1], acc[i][2], acc[i][3]};
        if (BIAS) {
            o.x += bias[n0 + tx4 + 0]; o.y += bias[n0 + tx4 + 1];
            o.z += bias[n0 + tx4 + 2]; o.w += bias[n0 + tx4 + 3];
        }
        *(float4*)(C + (size_t)row * N + n0 + tx4) = o;
    }
}

// ---------------------------------------------------------------------------
// Per-(h,row) stats over d=128: norm, mean (optional), unbiased-var ratio
// One wave per (h,row); 4 waves / block.
// ---------------------------------------------------------------------------
__global__ __launch_bounds__(256) void stats_kernel(const float* __restrict__ f,
                                                    float* __restrict__ norm_o,
                                                    float* __restrict__ mean_o,
                                                    float* __restrict__ ratio_o) {
    int hr = blockIdx.x * 4 + (threadIdx.x >> 6);
    int lane = threadIdx.x & 63;
    int h = hr >> 13;           // / 8192
    int r = hr & (R - 1);
    float2 v = *(const float2*)(f + (size_t)r * DIM + h * D + lane * 2);
    float sum = v.x + v.y;
    float sq = v.x * v.x + v.y * v.y;
    for (int off = 32; off; off >>= 1) {
        sum += __shfl_xor(sum, off);
        sq += __shfl_xor(sq, off);
    }
    if (lane == 0) {
        norm_o[hr] = sqrtf(sq);
        if (mean_o) mean_o[hr] = sum * (1.0f / D);
        float var = (sq - sum * sum * (1.0f / D)) * (1.0f / (D - 1));
        ratio_o[hr] = 2.0f * fminf(var, 1.0f) / (var + 1.0f);
    }
}

// ---------------------------------------------------------------------------
// Column mean over all 8192 rows per head: g[h,d] = mean_r f[r, h*D+d]
// ---------------------------------------------------------------------------
__global__ __launch_bounds__(128) void colmean_kernel(const float* __restrict__ f,
                                                      float* __restrict__ g) {
    int h = blockIdx.y;
    int r0 = blockIdx.x * 256;
    int d = threadIdx.x;
    float s = 0.0f;
    for (int r = 0; r < 256; r++)
        s += f[(size_t)(r0 + r) * DIM + h * D + d];
    atomicAdd(&g[h * D + d], s * (1.0f / R));
}

// ---------------------------------------------------------------------------
// feat_corr partial: fc[h,d,e] += sum_r qc[r,d]*qc[r,e]  (raw sum; /R later)
// blockIdx.x = 512-row chunk, blockIdx.y = h. 8x8 outputs per thread.
// ---------------------------------------------------------------------------
__global__ __launch_bounds__(256) void featcorr_kernel(const float* __restrict__ fq,
                                                       const float* __restrict__ qmean,
                                                       float* __restrict__ fc) {
    int h = blockIdx.y;
    int r0 = blockIdx.x * 512;
    int tid = threadIdx.x;
    int d0 = (tid >> 4) * 8, e0 = (tid & 15) * 8;
    __shared__ float Qc[32][128];
    float acc[8][8] = {};
    int lrow = tid >> 3;          // 0..31
    int lcol = (tid & 7) * 16;
    for (int rt = 0; rt < 512; rt += 32) {
        int r = r0 + rt + lrow;
        float mean = qmean[h * R + r];
        const float* src = fq + (size_t)r * DIM + h * D + lcol;
#pragma unroll
        for (int c = 0; c < 16; c += 4) {
            float4 v = *(const float4*)(src + c);
            Qc[lrow][lcol + c + 0] = v.x - mean;
            Qc[lrow][lcol + c + 1] = v.y - mean;
            Qc[lrow][lcol + c + 2] = v.z - mean;
            Qc[lrow][lcol + c + 3] = v.w - mean;
        }
        __syncthreads();
        for (int rr = 0; rr < 32; rr++) {
            float a_[8], b_[8];
#pragma unroll
            for (int i = 0; i < 8; i++) a_[i] = Qc[rr][d0 + i];
#pragma unroll
            for (int j = 0; j < 8; j++) b_[j] = Qc[rr][e0 + j];
#pragma unroll
            for (int i = 0; i < 8; i++)
#pragma unroll
                for (int j = 0; j < 8; j++)
                    acc[i][j] = fmaf(a_[i], b_[j], acc[i][j]);
        }
        __syncthreads();
    }
#pragma unroll
    for (int i = 0; i < 8; i++)
#pragma unroll
        for (int j = 0; j < 8; j++)
            atomicAdd(&fc[h * (D * D) + (d0 + i) * D + (e0 + j)], acc[i][j]);
}

// ---------------------------------------------------------------------------
// Per-head: decorr scale + weight-predictor MLP -> coef[h*2]={cw+vw*ds, ww}
// ---------------------------------------------------------------------------
__global__ __launch_bounds__(256) void head_kernel(const float* __restrict__ fc,
                                                   const float* __restrict__ qg,
                                                   const float* __restrict__ kg,
                                                   const float* __restrict__ w1,
                                                   const float* __restrict__ b1,
                                                   const float* __restrict__ lng,
                                                   const float* __restrict__ lnb,
                                                   const float* __restrict__ w2,
                                                   const float* __restrict__ b2,
                                                   float* __restrict__ coef) {
    int h = blockIdx.x, tid = threadIdx.x;
    __shared__ float s1[256], s2[256], s3[256];
    __shared__ float feats[256];
    // --- decorrelation score ---
    float S = 0.0f;
    for (int idx = tid; idx < D * D; idx += 256) {
        int dd = idx >> 7, ee = idx & 127;
        if (dd != ee) {
            float v = fc[h * (D * D) + idx] * (1.0f / R);
            S += v * v;
        }
    }
    s1[tid] = S;
    __syncthreads();
    for (int s = 128; s > 0; s >>= 1) {
        if (tid < s) s1[tid] += s1[tid + s];
        __syncthreads();
    }
    float dscale = expf(-5.0f * sqrtf(s1[0]) / (float)(D * D));
    __syncthreads();
    // --- predictor MLP ---
    feats[tid] = (tid < 128) ? qg[h * D + tid] : kg[h * D + tid - 128];
    __syncthreads();
    float yv = 0.0f;
    if (tid < 128) {
        float a = b1[tid];
        for (int i = 0; i < 256; i++) a = fmaf(feats[i], w1[tid * 256 + i], a);
        yv = a;
    }
    s1[tid] = (tid < 128) ? yv : 0.0f;
    s2[tid] = (tid < 128) ? yv * yv : 0.0f;
    __syncthreads();
    for (int s = 128; s > 0; s >>= 1) {
        if (tid < s) { s1[tid] += s1[tid + s]; s2[tid] += s2[tid + s]; }
        __syncthreads();
    }
    float mean = s1[0] * (1.0f / 128.0f);
    float var = s2[0] * (1.0f / 128.0f) - mean * mean;
    float rstd = rsqrtf(var + 1e-5f);
    float rel = 0.0f;
    if (tid < 128)
        rel = fmaxf((yv - mean) * rstd * lng[tid] + lnb[tid], 0.0f);
    __syncthreads();
    s1[tid] = (tid < 128) ? rel * w2[0 * 128 + tid] : 0.0f;
    s2[tid] = (tid < 128) ? rel * w2[1 * 128 + tid] : 0.0f;
    s3[tid] = (tid < 128) ? rel * w2[2 * 128 + tid] : 0.0f;
    __syncthreads();
    for (int s = 128; s > 0; s >>= 1) {
        if (tid < s) { s1[tid] += s1[tid + s]; s2[tid] += s2[tid + s]; s3[tid] += s3[tid + s]; }
        __syncthreads();
    }
    if (tid == 0) {
        float g0 = s1[0] + b2[0], g1 = s2[0] + b2[1], g2 = s3[0] + b2[2];
        float mx = fmaxf(g0, fmaxf(g1, g2));
        float e0 = expf(g0 - mx), e1 = expf(g1 - mx), e2 = expf(g2 - mx);
        float inv = 1.0f / (e0 + e1 + e2);
        coef[h * 2 + 0] = e0 * inv + e1 * inv * dscale;  // cw + vw*decorr_scale
        coef[h * 2 + 1] = e2 * inv;                      // ww
    }
}

// ---------------------------------------------------------------------------
// Per (h,qi): M[d,e] = sum_m (f_k[m,d]/kn[m]) * f_v[m,e]; s_v[e]=sum kr*f_v
// ---------------------------------------------------------------------------
__global__ __launch_bounds__(256) void ktv_kernel(const float* __restrict__ fk,
                                                  const float* __restrict__ fv,
                                                  const float* __restrict__ kn,
                                                  const float* __restrict__ kr,
                                                  float* __restrict__ Mout,
                                                  float* __restrict__ sv) {
    int qi = blockIdx.x, h = blockIdx.y;
    int tid = threadIdx.x;
    int d0 = (tid >> 4) * 8, e0 = (tid & 15) * 8;
    __shared__ float Ks[32][128], Vs[32][128];
    float acc[8][8] = {};
    int lrow = tid >> 3, lcol = (tid & 7) * 16;
    for (int mt = 0; mt < NSEQ; mt += 32) {
        int row = qi * NSEQ + mt + lrow;
        float invn = 1.0f / kn[h * R + row];
        const float* ksrc = fk + (size_t)row * DIM + h * D + lcol;
        const float* vsrc = fv + (size_t)row * DIM + h * D + lcol;
#pragma unroll
        for (int c = 0; c < 16; c += 4) {
            float4 a = *(const float4*)(ksrc + c);
            float4 b = *(const float4*)(vsrc + c);
            Ks[lrow][lcol + c + 0] = a.x * invn; Ks[lrow][lcol + c + 1] = a.y * invn;
            Ks[lrow][lcol + c + 2] = a.z * invn; Ks[lrow][lcol + c + 3] = a.w * invn;
            Vs[lrow][lcol + c + 0] = b.x; Vs[lrow][lcol + c + 1] = b.y;
            Vs[lrow][lcol + c + 2] = b.z; Vs[lrow][lcol + c + 3] = b.w;
        }
        __syncthreads();
        for (int rr = 0; rr < 32; rr++) {
            float a_[8], b_[8];
#pragma unroll
            for (int i = 0; i < 8; i++) a_[i] = Ks[rr][d0 + i];
#pragma unroll
            for (int j = 0; j < 8; j++) b_[j] = Vs[rr][e0 + j];
#pragma unroll
            for (int i = 0; i < 8; i++)
#pragma unroll
                for (int j = 0; j < 8; j++)
                    acc[i][j] = fmaf(a_[i], b_[j], acc[i][j]);
        }
        __syncthreads();
    }
    float* mb = Mout + (size_t)(h * QB + qi) * D * D;
#pragma unroll
    for (int i = 0; i < 8; i++) {
        float4 o0 = {acc[i][0], acc[i][1], acc[i][2], acc[i][3]};
        float4 o1 = {acc[i][4], acc[i][5], acc[i][6], acc[i][7]};
        *(float4*)(mb + (d0 + i) * D + e0) = o0;
        *(float4*)(mb + (d0 + i) * D + e0 + 4) = o1;
    }
    if (tid < D) {
        float s = 0.0f;
        for (int m = 0; m < NSEQ; m++) {
            int row = qi * NSEQ + m;
            s = fmaf(kr[h * R + row], fv[(size_t)row * DIM + h * D + tid], s);
        }
        sv[(h * QB + qi) * D + tid] = s;
    }
}

// ---------------------------------------------------------------------------
// outA[n,e] = coef0/qn[n] * (f_q[n,:] @ M) + coef1*q_ratio[n]*s_v[e]
// grid (nchunk=8, qi=16, h=8); 64 n-rows x 128 e per block; 4x8 per thread
// ---------------------------------------------------------------------------
__global__ __launch_bounds__(256) void attn_kernel(const float* __restrict__ fq,
                                                   const float* __restrict__ Mbuf,
                                                   const float* __restrict__ qn,
                                                   const float* __restrict__ qr,
                                                   const float* __restrict__ sv,
                                                   const float* __restrict__ coef,
                                                   float* __restrict__ aout) {
    int nb = blockIdx.x * 64;
    int qi = blockIdx.y, h = blockIdx.z;
    int tid = threadIdx.x;
    int tx = tid & 15, ty = tid >> 4;
    int e0 = tx * 8, ty4 = ty * 4;
    __shared__ float Ms[32][128];   // [d-chunk][e]
    __shared__ float Qs[32][68];    // transposed: [d-chunk][n]
    const float* mb = Mbuf + (size_t)(h * QB + qi) * D * D;
    float acc[4][8] = {};
    for (int dt = 0; dt < D; dt += 32) {
        {   // load M chunk: 32x128
            int mrow = tid >> 3, mcol = (tid & 7) * 16;
#pragma unroll
            for (int c = 0; c < 16; c += 4)
                *(float4*)&Ms[mrow][mcol + c] = *(const float4*)(mb + (dt + mrow) * D + mcol + c);
        }
        {   // load Q chunk transposed: 64 n x 32 d
            int qrow = tid >> 2;          // 0..63 (n)
            int qcol = (tid & 3) * 8;     // 0..24 (d)
            const float* src = fq + (size_t)(qi * NSEQ + nb + qrow) * DIM + h * D + dt + qcol;
            float4 v0 = *(const float4*)(src);
            float4 v1 = *(const float4*)(src + 4);
            Qs[qcol + 0][qrow] = v0.x; Qs[qcol + 1][qrow] = v0.y;
            Qs[qcol + 2][qrow] = v0.z; Qs[qcol + 3][qrow] = v0.w;
            Qs[qcol + 4][qrow] = v1.x; Qs[qcol + 5][qrow] = v1.y;
            Qs[qcol + 6][qrow] = v1.z; Qs[qcol + 7][qrow] = v1.w;
        }
        __syncthreads();
        for (int d = 0; d < 32; d++) {
            float4 b0 = *(const float4*)&Ms[d][e0];
            float4 b1 = *(const float4*)&Ms[d][e0 + 4];
            float b_[8] = {b0.x, b0.y, b0.z, b0.w, b1.x, b1.y, b1.z, b1.w};
            float a_[4];
#pragma unroll
            for (int i = 0; i < 4; i++) a_[i] = Qs[d][ty4 + i];
#pragma unroll
            for (int i = 0; i < 4; i++)
#pragma unroll
                for (int j = 0; j < 8; j++)
                    acc[i][j] = fmaf(a_[i], b_[j], acc[i][j]);
        }
        __syncthreads();
    }
    int base = h * R + qi * NSEQ;
    float c0 = coef[2 * h], c1 = coef[2 * h + 1];
    float4 sv0 = *(const float4*)(sv + (h * QB + qi) * D + e0);
    float4 sv1 = *(const float4*)(sv + (h * QB + qi) * D + e0 + 4);
    float sv_[8] = {sv0.x, sv0.y, sv0.z, sv0.w, sv1.x, sv1.y, sv1.z, sv1.w};
#pragma unroll
    for (int i = 0; i < 4; i++) {
        int n = nb + ty4 + i;
        float sc1 = c0 / qn[base + n];
        float sc2 = c1 * qr[base + n];
        float o[8];
#pragma unroll
        for (int j = 0; j < 8; j++) o[j] = sc1 * acc[i][j] + sc2 * sv_[j];
        float* dst = aout + (size_t)(qi * NSEQ + n) * DIM + h * D + e0;
        *(float4*)(dst) = make_float4(o[0], o[1], o[2], o[3]);
        *(float4*)(dst + 4) = make_float4(o[4], o[5], o[6], o[7]);
    }
}

// ---------------------------------------------------------------------------
extern "C" void kernel_launch(void* const* d_in, const int* in_sizes, int n_in,
                              void* d_out, int out_size, void* d_ws, size_t ws_size,
                              hipStream_t stream) {
    (void)in_sizes; (void)n_in; (void)out_size; (void)ws_size;
    const float* q      = (const float*)d_in[0];
    const float* k      = (const float*)d_in[1];
    const float* v      = (const float*)d_in[2];
    const float* ln_g   = (const float*)d_in[3];
    const float* ln_b   = (const float*)d_in[4];
    const float* w_in   = (const float*)d_in[5];
    const float* wp_w1  = (const float*)d_in[6];
    const float* wp_b1  = (const float*)d_in[7];
    const float* wp_lng = (const float*)d_in[8];
    const float* wp_lnb = (const float*)d_in[9];
    const float* wp_w2  = (const float*)d_in[10];
    const float* wp_b2  = (const float*)d_in[11];
    const float* w_out  = (const float*)d_in[12];
    const float* b_out  = (const float*)d_in[13];
    float* out = (float*)d_out;
    float* ws = (float*)d_ws;

    constexpr size_t F = (size_t)R * DIM;      // 8388608
    float* f_q   = ws;
    float* f_k   = ws + F;
    float* f_v   = ws + 2 * F;
    float* lnbuf = ws + 3 * F;                 // LN scratch, reused as attn_out
    float* Mbuf  = ws + 4 * F;                 // H*QB*D*D = 2097152
    float* sv    = Mbuf + (size_t)H * QB * D * D;
    float* qn    = sv + H * QB * D;
    float* qm    = qn + HR;
    float* qr    = qm + HR;
    float* kn    = qr + HR;
    float* kr    = kn + HR;
    float* qg    = kr + HR;                    // H*D
    float* kg    = qg + H * D;                 // H*D
    float* fc    = kg + H * D;                 // H*D*D
    float* coef  = fc + (size_t)H * D * D;     // 16

    // zero the atomic-accumulated buffers (qg, kg, fc are contiguous)
    hipMemsetAsync(qg, 0, (size_t)(2 * H * D + H * D * D) * sizeof(float), stream);

    dim3 gemmGrid(DIM / 64, R / 64);

    ln_kernel<<<R, 256, 0, stream>>>(q, ln_g, ln_b, lnbuf);
    gemm_nt<0><<<gemmGrid, 256, 0, stream>>>(lnbuf, w_in, nullptr, f_q, R, DIM, DIM);
    ln_kernel<<<R, 256, 0, stream>>>(k, ln_g, ln_b, lnbuf);
    gemm_nt<0><<<gemmGrid, 256, 0, stream>>>(lnbuf, w_in, nullptr, f_k, R, DIM, DIM);
    ln_kernel<<<R, 256, 0, stream>>>(v, ln_g, ln_b, lnbuf);
    gemm_nt<0><<<gemmGrid, 256, 0, stream>>>(lnbuf, w_in, nullptr, f_v, R, DIM, DIM);

    stats_kernel<<<HR / 4, 256, 0, stream>>>(f_q, qn, qm, qr);
    stats_kernel<<<HR / 4, 256, 0, stream>>>(f_k, kn, nullptr, kr);

    colmean_kernel<<<dim3(32, H), 128, 0, stream>>>(f_q, qg);
    colmean_kernel<<<dim3(32, H), 128, 0, stream>>>(f_k, kg);

    featcorr_kernel<<<dim3(16, H), 256, 0, stream>>>(f_q, qm, fc);

    head_kernel<<<H, 256, 0, stream>>>(fc, qg, kg, wp_w1, wp_b1, wp_lng, wp_lnb,
                                       wp_w2, wp_b2, coef);

    ktv_kernel<<<dim3(QB, H), 256, 0, stream>>>(f_k, f_v, kn, kr, Mbuf, sv);

    attn_kernel<<<dim3(NSEQ / 64, QB, H), 256, 0, stream>>>(f_q, Mbuf, qn, qr, sv,
                                                            coef, lnbuf);

    gemm_nt<1><<<gemmGrid, 256, 0, stream>>>(lnbuf, w_out, b_out, out, R, DIM, DIM);
}

// Round 2
// 636.408 us; speedup vs baseline: 2.2563x; 2.2563x over previous
//
#include <hip/hip_runtime.h>
#include <hip/hip_bf16.h>

#define H 8
#define D 128
#define DIM 1024
#define QB 16
#define NSEQ 512
#define R (QB * NSEQ)      /* 8192 rows */
#define HR (H * R)         /* 65536 (h,row) pairs */

typedef __attribute__((ext_vector_type(8))) short short8;
typedef __attribute__((ext_vector_type(4))) float floatx4;

__device__ inline unsigned short f2b(float x) {
    union { float f; unsigned int u; } c{x};
    unsigned int lsb = (c.u >> 16) & 1;
    unsigned int r = c.u + 0x7fffu + lsb;   // round-to-nearest-even
    return (unsigned short)(r >> 16);
}

#define GLOAD_LDS16(gptr, lptr)                                                        \
    __builtin_amdgcn_global_load_lds(                                                  \
        (const __attribute__((address_space(1))) unsigned int*)(gptr),                 \
        (__attribute__((address_space(3))) unsigned int*)(lptr), 16, 0, 0)

// ---------------------------------------------------------------------------
// LayerNorm over DIM=1024, one block (256 thr) per row -> bf16 output
// ---------------------------------------------------------------------------
__global__ __launch_bounds__(256) void ln_kernel(const float* __restrict__ x,
                                                 const float* __restrict__ g,
                                                 const float* __restrict__ b,
                                                 unsigned short* __restrict__ out) {
    int r = blockIdx.x;
    int tid = threadIdx.x;
    const float* row = x + (size_t)r * DIM;
    float4 v = *(const float4*)(row + tid * 4);
    float sum = v.x + v.y + v.z + v.w;
    float sq = v.x * v.x + v.y * v.y + v.z * v.z + v.w * v.w;
    __shared__ float s1[256], s2[256];
    s1[tid] = sum; s2[tid] = sq;
    __syncthreads();
    for (int s = 128; s > 0; s >>= 1) {
        if (tid < s) { s1[tid] += s1[tid + s]; s2[tid] += s2[tid + s]; }
        __syncthreads();
    }
    float mean = s1[0] * (1.0f / DIM);
    float var = s2[0] * (1.0f / DIM) - mean * mean;
    float rstd = rsqrtf(var + 1e-5f);
    float4 gv = *(const float4*)(g + tid * 4);
    float4 bv = *(const float4*)(b + tid * 4);
    union { ushort4 u; unsigned short s[4]; } pk;
    pk.s[0] = f2b((v.x - mean) * rstd * gv.x + bv.x);
    pk.s[1] = f2b((v.y - mean) * rstd * gv.y + bv.y);
    pk.s[2] = f2b((v.z - mean) * rstd * gv.z + bv.z);
    pk.s[3] = f2b((v.w - mean) * rstd * gv.w + bv.w);
    *(ushort4*)(out + (size_t)r * DIM + tid * 4) = pk.u;
}

// ---------------------------------------------------------------------------
// fp32 -> bf16 weight conversion (grid-stride over n/4)
// ---------------------------------------------------------------------------
__global__ __launch_bounds__(256) void cvt_kernel(const float* __restrict__ in,
                                                  unsigned short* __restrict__ out,
                                                  int n4) {
    int i = blockIdx.x * 256 + threadIdx.x;
    if (i >= n4) return;
    float4 v = *(const float4*)(in + (size_t)i * 4);
    union { ushort4 u; unsigned short s[4]; } pk;
    pk.s[0] = f2b(v.x); pk.s[1] = f2b(v.y); pk.s[2] = f2b(v.z); pk.s[3] = f2b(v.w);
    *(ushort4*)(out + (size_t)i * 4) = pk.u;
}

// ---------------------------------------------------------------------------
// C[M,N] = A[M,K] @ B[N,K]^T (+ bias[n]); bf16 in, fp32 out.
// m97 structure: 128x128 tile, BK=32, 16x16x32 bf16 MFMA, 4 waves, 4x4
// tiles/wave, global_load_lds width=16 staging.
// ---------------------------------------------------------------------------
template <int BIAS>
__global__ __launch_bounds__(256) void gemm_bt_mfma(const unsigned short* __restrict__ A,
                                                    const unsigned short* __restrict__ B,
                                                    const float* __restrict__ bias,
                                                    float* __restrict__ C,
                                                    int M, int N, int K) {
    __shared__ unsigned short As[128 * 32];
    __shared__ unsigned short Bs[128 * 32];
    const int tid = threadIdx.x;
    const int m0 = blockIdx.y * 128, n0 = blockIdx.x * 128;
    const int wave = tid >> 6, lane = tid & 63;
    const int wm = (wave >> 1) * 64, wn = (wave & 1) * 64;
    const int fr = lane & 15, kq = lane >> 4;   // fragment row / k-quad

    // staging: element e = j*256 + tid covers 8 bf16; row = e>>2, chunk = e&3
    const int srow = tid >> 2;          // 0..63
    const int scol = (tid & 3) * 8;     // 0,8,16,24

    floatx4 acc[4][4] = {};

    const size_t aOff0 = (size_t)(m0 + srow) * K + scol;
    const size_t aOff1 = (size_t)(m0 + 64 + srow) * K + scol;
    const size_t bOff0 = (size_t)(n0 + srow) * K + scol;
    const size_t bOff1 = (size_t)(n0 + 64 + srow) * K + scol;
    unsigned short* lA0 = As + (size_t)tid * 8;          // byte off = tid*16
    unsigned short* lA1 = As + (size_t)(256 + tid) * 8;
    unsigned short* lB0 = Bs + (size_t)tid * 8;
    unsigned short* lB1 = Bs + (size_t)(256 + tid) * 8;

    for (int kt = 0; kt < K; kt += 32) {
        GLOAD_LDS16(A + aOff0 + kt, lA0);
        GLOAD_LDS16(A + aOff1 + kt, lA1);
        GLOAD_LDS16(B + bOff0 + kt, lB0);
        GLOAD_LDS16(B + bOff1 + kt, lB1);
        __syncthreads();
        short8 af[4], bf[4];
#pragma unroll
        for (int i = 0; i < 4; i++)
            af[i] = *(const short8*)&As[(wm + i * 16 + fr) * 32 + kq * 8];
#pragma unroll
        for (int j = 0; j < 4; j++)
            bf[j] = *(const short8*)&Bs[(wn + j * 16 + fr) * 32 + kq * 8];
#pragma unroll
        for (int i = 0; i < 4; i++)
#pragma unroll
            for (int j = 0; j < 4; j++)
                acc[i][j] = __builtin_amdgcn_mfma_f32_16x16x32_bf16(af[i], bf[j], acc[i][j], 0, 0, 0);
        __syncthreads();
    }
    // C/D layout: col = lane&15, row = (lane>>4)*4 + reg   [m89/m91 verified]
#pragma unroll
    for (int i = 0; i < 4; i++) {
        int rbase = m0 + wm + i * 16 + kq * 4;
#pragma unroll
        for (int j = 0; j < 4; j++) {
            int col = n0 + wn + j * 16 + fr;
            float badd = BIAS ? bias[col] : 0.0f;
#pragma unroll
            for (int r = 0; r < 4; r++)
                C[(size_t)(rbase + r) * N + col] = acc[i][j][r] + badd;
        }
    }
}

// ---------------------------------------------------------------------------
// Per-(h,row) stats over d=128: norm, mean (optional), unbiased-var ratio
// ---------------------------------------------------------------------------
__global__ __launch_bounds__(256) void stats_kernel(const float* __restrict__ f,
                                                    float* __restrict__ norm_o,
                                                    float* __restrict__ mean_o,
                                                    float* __restrict__ ratio_o) {
    int hr = blockIdx.x * 4 + (threadIdx.x >> 6);
    int lane = threadIdx.x & 63;
    int h = hr >> 13;
    int r = hr & (R - 1);
    float2 v = *(const float2*)(f + (size_t)r * DIM + h * D + lane * 2);
    float sum = v.x + v.y;
    float sq = v.x * v.x + v.y * v.y;
    for (int off = 32; off; off >>= 1) {
        sum += __shfl_xor(sum, off);
        sq += __shfl_xor(sq, off);
    }
    if (lane == 0) {
        norm_o[hr] = sqrtf(sq);
        if (mean_o) mean_o[hr] = sum * (1.0f / D);
        float var = (sq - sum * sum * (1.0f / D)) * (1.0f / (D - 1));
        ratio_o[hr] = 2.0f * fminf(var, 1.0f) / (var + 1.0f);
    }
}

// ---------------------------------------------------------------------------
__global__ __launch_bounds__(128) void colmean_kernel(const float* __restrict__ f,
                                                      float* __restrict__ g) {
    int h = blockIdx.y;
    int r0 = blockIdx.x * 256;
    int d = threadIdx.x;
    float s = 0.0f;
    for (int r = 0; r < 256; r++)
        s += f[(size_t)(r0 + r) * DIM + h * D + d];
    atomicAdd(&g[h * D + d], s * (1.0f / R));
}

// ---------------------------------------------------------------------------
__global__ __launch_bounds__(256) void featcorr_kernel(const float* __restrict__ fq,
                                                       const float* __restrict__ qmean,
                                                       float* __restrict__ fc) {
    int h = blockIdx.y;
    int r0 = blockIdx.x * 512;
    int tid = threadIdx.x;
    int d0 = (tid >> 4) * 8, e0 = (tid & 15) * 8;
    __shared__ float Qc[32][128];
    float acc[8][8] = {};
    int lrow = tid >> 3;
    int lcol = (tid & 7) * 16;
    for (int rt = 0; rt < 512; rt += 32) {
        int r = r0 + rt + lrow;
        float mean = qmean[h * R + r];
        const float* src = fq + (size_t)r * DIM + h * D + lcol;
#pragma unroll
        for (int c = 0; c < 16; c += 4) {
            float4 v = *(const float4*)(src + c);
            Qc[lrow][lcol + c + 0] = v.x - mean;
            Qc[lrow][lcol + c + 1] = v.y - mean;
            Qc[lrow][lcol + c + 2] = v.z - mean;
            Qc[lrow][lcol + c + 3] = v.w - mean;
        }
        __syncthreads();
        for (int rr = 0; rr < 32; rr++) {
            float a_[8], b_[8];
#pragma unroll
            for (int i = 0; i < 8; i++) a_[i] = Qc[rr][d0 + i];
#pragma unroll
            for (int j = 0; j < 8; j++) b_[j] = Qc[rr][e0 + j];
#pragma unroll
            for (int i = 0; i < 8; i++)
#pragma unroll
                for (int j = 0; j < 8; j++)
                    acc[i][j] = fmaf(a_[i], b_[j], acc[i][j]);
        }
        __syncthreads();
    }
#pragma unroll
    for (int i = 0; i < 8; i++)
#pragma unroll
        for (int j = 0; j < 8; j++)
            atomicAdd(&fc[h * (D * D) + (d0 + i) * D + (e0 + j)], acc[i][j]);
}

// ---------------------------------------------------------------------------
__global__ __launch_bounds__(256) void head_kernel(const float* __restrict__ fc,
                                                   const float* __restrict__ qg,
                                                   const float* __restrict__ kg,
                                                   const float* __restrict__ w1,
                                                   const float* __restrict__ b1,
                                                   const float* __restrict__ lng,
                                                   const float* __restrict__ lnb,
                                                   const float* __restrict__ w2,
                                                   const float* __restrict__ b2,
                                                   float* __restrict__ coef) {
    int h = blockIdx.x, tid = threadIdx.x;
    __shared__ float s1[256], s2[256], s3[256];
    __shared__ float feats[256];
    float S = 0.0f;
    for (int idx = tid; idx < D * D; idx += 256) {
        int dd = idx >> 7, ee = idx & 127;
        if (dd != ee) {
            float v = fc[h * (D * D) + idx] * (1.0f / R);
            S += v * v;
        }
    }
    s1[tid] = S;
    __syncthreads();
    for (int s = 128; s > 0; s >>= 1) {
        if (tid < s) s1[tid] += s1[tid + s];
        __syncthreads();
    }
    float dscale = expf(-5.0f * sqrtf(s1[0]) / (float)(D * D));
    __syncthreads();
    feats[tid] = (tid < 128) ? qg[h * D + tid] : kg[h * D + tid - 128];
    __syncthreads();
    float yv = 0.0f;
    if (tid < 128) {
        float a = b1[tid];
        for (int i = 0; i < 256; i++) a = fmaf(feats[i], w1[tid * 256 + i], a);
        yv = a;
    }
    s1[tid] = (tid < 128) ? yv : 0.0f;
    s2[tid] = (tid < 128) ? yv * yv : 0.0f;
    __syncthreads();
    for (int s = 128; s > 0; s >>= 1) {
        if (tid < s) { s1[tid] += s1[tid + s]; s2[tid] += s2[tid + s]; }
        __syncthreads();
    }
    float mean = s1[0] * (1.0f / 128.0f);
    float var = s2[0] * (1.0f / 128.0f) - mean * mean;
    float rstd = rsqrtf(var + 1e-5f);
    float rel = 0.0f;
    if (tid < 128)
        rel = fmaxf((yv - mean) * rstd * lng[tid] + lnb[tid], 0.0f);
    __syncthreads();
    s1[tid] = (tid < 128) ? rel * w2[0 * 128 + tid] : 0.0f;
    s2[tid] = (tid < 128) ? rel * w2[1 * 128 + tid] : 0.0f;
    s3[tid] = (tid < 128) ? rel * w2[2 * 128 + tid] : 0.0f;
    __syncthreads();
    for (int s = 128; s > 0; s >>= 1) {
        if (tid < s) { s1[tid] += s1[tid + s]; s2[tid] += s2[tid + s]; s3[tid] += s3[tid + s]; }
        __syncthreads();
    }
    if (tid == 0) {
        float g0 = s1[0] + b2[0], g1 = s2[0] + b2[1], g2 = s3[0] + b2[2];
        float mx = fmaxf(g0, fmaxf(g1, g2));
        float e0 = expf(g0 - mx), e1 = expf(g1 - mx), e2 = expf(g2 - mx);
        float inv = 1.0f / (e0 + e1 + e2);
        coef[h * 2 + 0] = e0 * inv + e1 * inv * dscale;  // cw + vw*decorr_scale
        coef[h * 2 + 1] = e2 * inv;                      // ww
    }
}

// ---------------------------------------------------------------------------
__global__ __launch_bounds__(256) void ktv_kernel(const float* __restrict__ fk,
                                                  const float* __restrict__ fv,
                                                  const float* __restrict__ kn,
                                                  const float* __restrict__ kr,
                                                  float* __restrict__ Mout,
                                                  float* __restrict__ sv) {
    int qi = blockIdx.x, h = blockIdx.y;
    int tid = threadIdx.x;
    int d0 = (tid >> 4) * 8, e0 = (tid & 15) * 8;
    __shared__ float Ks[32][128], Vs[32][128];
    float acc[8][8] = {};
    int lrow = tid >> 3, lcol = (tid & 7) * 16;
    for (int mt = 0; mt < NSEQ; mt += 32) {
        int row = qi * NSEQ + mt + lrow;
        float invn = 1.0f / kn[h * R + row];
        const float* ksrc = fk + (size_t)row * DIM + h * D + lcol;
        const float* vsrc = fv + (size_t)row * DIM + h * D + lcol;
#pragma unroll
        for (int c = 0; c < 16; c += 4) {
            float4 a = *(const float4*)(ksrc + c);
            float4 b = *(const float4*)(vsrc + c);
            Ks[lrow][lcol + c + 0] = a.x * invn; Ks[lrow][lcol + c + 1] = a.y * invn;
            Ks[lrow][lcol + c + 2] = a.z * invn; Ks[lrow][lcol + c + 3] = a.w * invn;
            Vs[lrow][lcol + c + 0] = b.x; Vs[lrow][lcol + c + 1] = b.y;
            Vs[lrow][lcol + c + 2] = b.z; Vs[lrow][lcol + c + 3] = b.w;
        }
        __syncthreads();
        for (int rr = 0; rr < 32; rr++) {
            float a_[8], b_[8];
#pragma unroll
            for (int i = 0; i < 8; i++) a_[i] = Ks[rr][d0 + i];
#pragma unroll
            for (int j = 0; j < 8; j++) b_[j] = Vs[rr][e0 + j];
#pragma unroll
            for (int i = 0; i < 8; i++)
#pragma unroll
                for (int j = 0; j < 8; j++)
                    acc[i][j] = fmaf(a_[i], b_[j], acc[i][j]);
        }
        __syncthreads();
    }
    float* mb = Mout + (size_t)(h * QB + qi) * D * D;
#pragma unroll
    for (int i = 0; i < 8; i++) {
        float4 o0 = {acc[i][0], acc[i][1], acc[i][2], acc[i][3]};
        float4 o1 = {acc[i][4], acc[i][5], acc[i][6], acc[i][7]};
        *(float4*)(mb + (d0 + i) * D + e0) = o0;
        *(float4*)(mb + (d0 + i) * D + e0 + 4) = o1;
    }
    if (tid < D) {
        float s = 0.0f;
        for (int m = 0; m < NSEQ; m++) {
            int row = qi * NSEQ + m;
            s = fmaf(kr[h * R + row], fv[(size_t)row * DIM + h * D + tid], s);
        }
        sv[(h * QB + qi) * D + tid] = s;
    }
}

// ---------------------------------------------------------------------------
// outA[n,e] = coef0/qn[n] * (f_q[n,:] @ M) + coef1*q_ratio[n]*s_v[e] -> bf16
// ---------------------------------------------------------------------------
__global__ __launch_bounds__(256) void attn_kernel(const float* __restrict__ fq,
                                                   const float* __restrict__ Mbuf,
                                                   const float* __restrict__ qn,
                                                   const float* __restrict__ qr,
                                                   const float* __restrict__ sv,
                                                   const float* __restrict__ coef,
                                                   unsigned short* __restrict__ aout) {
    int nb = blockIdx.x * 64;
    int qi = blockIdx.y, h = blockIdx.z;
    int tid = threadIdx.x;
    int tx = tid & 15, ty = tid >> 4;
    int e0 = tx * 8, ty4 = ty * 4;
    __shared__ float Ms[32][128];
    __shared__ float Qs[32][68];
    const float* mb = Mbuf + (size_t)(h * QB + qi) * D * D;
    float acc[4][8] = {};
    for (int dt = 0; dt < D; dt += 32) {
        {
            int mrow = tid >> 3, mcol = (tid & 7) * 16;
#pragma unroll
            for (int c = 0; c < 16; c += 4)
                *(float4*)&Ms[mrow][mcol + c] = *(const float4*)(mb + (dt + mrow) * D + mcol + c);
        }
        {
            int qrow = tid >> 2;
            int qcol = (tid & 3) * 8;
            const float* src = fq + (size_t)(qi * NSEQ + nb + qrow) * DIM + h * D + dt + qcol;
            float4 v0 = *(const float4*)(src);
            float4 v1 = *(const float4*)(src + 4);
            Qs[qcol + 0][qrow] = v0.x; Qs[qcol + 1][qrow] = v0.y;
            Qs[qcol + 2][qrow] = v0.z; Qs[qcol + 3][qrow] = v0.w;
            Qs[qcol + 4][qrow] = v1.x; Qs[qcol + 5][qrow] = v1.y;
            Qs[qcol + 6][qrow] = v1.z; Qs[qcol + 7][qrow] = v1.w;
        }
        __syncthreads();
        for (int d = 0; d < 32; d++) {
            float4 b0 = *(const float4*)&Ms[d][e0];
            float4 b1 = *(const float4*)&Ms[d][e0 + 4];
            float b_[8] = {b0.x, b0.y, b0.z, b0.w, b1.x, b1.y, b1.z, b1.w};
            float a_[4];
#pragma unroll
            for (int i = 0; i < 4; i++) a_[i] = Qs[d][ty4 + i];
#pragma unroll
            for (int i = 0; i < 4; i++)
#pragma unroll
                for (int j = 0; j < 8; j++)
                    acc[i][j] = fmaf(a_[i], b_[j], acc[i][j]);
        }
        __syncthreads();
    }
    int base = h * R + qi * NSEQ;
    float c0 = coef[2 * h], c1 = coef[2 * h + 1];
    float4 sv0 = *(const float4*)(sv + (h * QB + qi) * D + e0);
    float4 sv1 = *(const float4*)(sv + (h * QB + qi) * D + e0 + 4);
    float sv_[8] = {sv0.x, sv0.y, sv0.z, sv0.w, sv1.x, sv1.y, sv1.z, sv1.w};
#pragma unroll
    for (int i = 0; i < 4; i++) {
        int n = nb + ty4 + i;
        float sc1 = c0 / qn[base + n];
        float sc2 = c1 * qr[base + n];
        union { uint4 v; unsigned short s[8]; } pk;
#pragma unroll
        for (int j = 0; j < 8; j++) pk.s[j] = f2b(sc1 * acc[i][j] + sc2 * sv_[j]);
        unsigned short* dst = aout + (size_t)(qi * NSEQ + n) * DIM + h * D + e0;
        *(uint4*)dst = pk.v;
    }
}

// ---------------------------------------------------------------------------
extern "C" void kernel_launch(void* const* d_in, const int* in_sizes, int n_in,
                              void* d_out, int out_size, void* d_ws, size_t ws_size,
                              hipStream_t stream) {
    (void)in_sizes; (void)n_in; (void)out_size; (void)ws_size;
    const float* q      = (const float*)d_in[0];
    const float* k      = (const float*)d_in[1];
    const float* v      = (const float*)d_in[2];
    const float* ln_g   = (const float*)d_in[3];
    const float* ln_b   = (const float*)d_in[4];
    const float* w_in   = (const float*)d_in[5];
    const float* wp_w1  = (const float*)d_in[6];
    const float* wp_b1  = (const float*)d_in[7];
    const float* wp_lng = (const float*)d_in[8];
    const float* wp_lnb = (const float*)d_in[9];
    const float* wp_w2  = (const float*)d_in[10];
    const float* wp_b2  = (const float*)d_in[11];
    const float* w_out  = (const float*)d_in[12];
    const float* b_out  = (const float*)d_in[13];
    float* out = (float*)d_out;
    float* ws = (float*)d_ws;

    constexpr size_t F = (size_t)R * DIM;             // 8388608 floats
    float* f_q   = ws;
    float* f_k   = ws + F;
    float* f_v   = ws + 2 * F;
    float* Mbuf  = ws + 3 * F;                        // H*QB*D*D = 2097152
    float* sv    = Mbuf + (size_t)H * QB * D * D;     // 16384
    float* qn    = sv + H * QB * D;
    float* qm    = qn + HR;
    float* qr    = qm + HR;
    float* kn    = qr + HR;
    float* kr    = kn + HR;
    float* qg    = kr + HR;                           // H*D
    float* kg    = qg + H * D;                        // H*D
    float* fc    = kg + H * D;                        // H*D*D
    float* coef  = fc + (size_t)H * D * D;            // 16 -> pad 64
    // bf16 region (aligned: all offsets are multiples of 16 floats)
    unsigned short* xb16   = (unsigned short*)(coef + 64);        // R*DIM bf16 (LN out, later attn out)
    unsigned short* w_in16 = xb16 + F;                             // 1M bf16
    unsigned short* w_out16 = w_in16 + (size_t)DIM * DIM;          // 1M bf16

    // zero atomic-accumulated buffers (qg, kg, fc contiguous)
    hipMemsetAsync(qg, 0, (size_t)(2 * H * D + H * D * D) * sizeof(float), stream);

    // weight conversion
    cvt_kernel<<<(DIM * DIM / 4 + 255) / 256, 256, 0, stream>>>(w_in, w_in16, DIM * DIM / 4);
    cvt_kernel<<<(DIM * DIM / 4 + 255) / 256, 256, 0, stream>>>(w_out, w_out16, DIM * DIM / 4);

    dim3 gemmGrid(DIM / 128, R / 128);   // (8, 64)

    ln_kernel<<<R, 256, 0, stream>>>(q, ln_g, ln_b, xb16);
    gemm_bt_mfma<0><<<gemmGrid, 256, 0, stream>>>(xb16, w_in16, nullptr, f_q, R, DIM, DIM);
    ln_kernel<<<R, 256, 0, stream>>>(k, ln_g, ln_b, xb16);
    gemm_bt_mfma<0><<<gemmGrid, 256, 0, stream>>>(xb16, w_in16, nullptr, f_k, R, DIM, DIM);
    ln_kernel<<<R, 256, 0, stream>>>(v, ln_g, ln_b, xb16);
    gemm_bt_mfma<0><<<gemmGrid, 256, 0, stream>>>(xb16, w_in16, nullptr, f_v, R, DIM, DIM);

    stats_kernel<<<HR / 4, 256, 0, stream>>>(f_q, qn, qm, qr);
    stats_kernel<<<HR / 4, 256, 0, stream>>>(f_k, kn, nullptr, kr);

    colmean_kernel<<<dim3(32, H), 128, 0, stream>>>(f_q, qg);
    colmean_kernel<<<dim3(32, H), 128, 0, stream>>>(f_k, kg);

    featcorr_kernel<<<dim3(16, H), 256, 0, stream>>>(f_q, qm, fc);

    head_kernel<<<H, 256, 0, stream>>>(fc, qg, kg, wp_w1, wp_b1, wp_lng, wp_lnb,
                                       wp_w2, wp_b2, coef);

    ktv_kernel<<<dim3(QB, H), 256, 0, stream>>>(f_k, f_v, kn, kr, Mbuf, sv);

    attn_kernel<<<dim3(NSEQ / 64, QB, H), 256, 0, stream>>>(f_q, Mbuf, qn, qr, sv,
                                                            coef, xb16);

    gemm_bt_mfma<1><<<gemmGrid, 256, 0, stream>>>(xb16, w_out16, b_out, out, R, DIM, DIM);
}

// Round 3
// 410.988 us; speedup vs baseline: 3.4938x; 1.5485x over previous
//
#include <hip/hip_runtime.h>
#include <hip/hip_bf16.h>

typedef unsigned short u16;
typedef __attribute__((ext_vector_type(8))) short short8;
typedef __attribute__((ext_vector_type(4))) float floatx4;

#define H 8
#define D 128
#define DIM 1024
#define QB 16
#define NSEQ 512
#define R 8192            /* QB*NSEQ rows */

__device__ inline u16 f2b(float x) {
    union { float f; unsigned int u; } c{x};
    unsigned int lsb = (c.u >> 16) & 1;
    unsigned int r = c.u + 0x7fffu + lsb;   // round-to-nearest-even
    return (u16)(r >> 16);
}
__device__ inline float b2f(u16 u) {
    union { unsigned int i; float f; } c;
    c.i = (unsigned int)u << 16;
    return c.f;
}

#define GLOAD_LDS16(gptr, lptr)                                                        \
    __builtin_amdgcn_global_load_lds(                                                  \
        (const __attribute__((address_space(1))) unsigned int*)(gptr),                 \
        (__attribute__((address_space(3))) unsigned int*)(lptr), 16, 0, 0)

// ---------------------------------------------------------------------------
// LayerNorm over DIM=1024, one block per row -> bf16
// ---------------------------------------------------------------------------
__global__ __launch_bounds__(256) void ln_kernel(const float* __restrict__ x,
                                                 const float* __restrict__ g,
                                                 const float* __restrict__ b,
                                                 u16* __restrict__ out) {
    int r = blockIdx.x;
    int tid = threadIdx.x;
    const float* row = x + (size_t)r * DIM;
    float4 v = *(const float4*)(row + tid * 4);
    float sum = v.x + v.y + v.z + v.w;
    float sq = v.x * v.x + v.y * v.y + v.z * v.z + v.w * v.w;
    __shared__ float s1[256], s2[256];
    s1[tid] = sum; s2[tid] = sq;
    __syncthreads();
    for (int s = 128; s > 0; s >>= 1) {
        if (tid < s) { s1[tid] += s1[tid + s]; s2[tid] += s2[tid + s]; }
        __syncthreads();
    }
    float mean = s1[0] * (1.0f / DIM);
    float var = s2[0] * (1.0f / DIM) - mean * mean;
    float rstd = rsqrtf(var + 1e-5f);
    float4 gv = *(const float4*)(g + tid * 4);
    float4 bv = *(const float4*)(b + tid * 4);
    ushort4 pk;
    pk.x = f2b((v.x - mean) * rstd * gv.x + bv.x);
    pk.y = f2b((v.y - mean) * rstd * gv.y + bv.y);
    pk.z = f2b((v.z - mean) * rstd * gv.z + bv.z);
    pk.w = f2b((v.w - mean) * rstd * gv.w + bv.w);
    *(ushort4*)(out + (size_t)r * DIM + tid * 4) = pk;
}

// ---------------------------------------------------------------------------
__global__ __launch_bounds__(256) void cvt_kernel(const float* __restrict__ in,
                                                  u16* __restrict__ out, int n4) {
    int i = blockIdx.x * 256 + threadIdx.x;
    if (i >= n4) return;
    float4 v = *(const float4*)(in + (size_t)i * 4);
    ushort4 pk;
    pk.x = f2b(v.x); pk.y = f2b(v.y); pk.z = f2b(v.z); pk.w = f2b(v.w);
    *(ushort4*)(out + (size_t)i * 4) = pk;
}

// ---------------------------------------------------------------------------
// C = A[8192,1024] @ B[1024,1024]^T ; bf16 in, 128x128 tile, BK=32, MFMA.
// MODE 0 (Q): write Ct=qT[h][d][r] + Cr=row-major bf16
// MODE 1 (K): write Ct=kT only
// MODE 2 (V): write Ct=vT' = V/kn[row] (kn from stats_k)
// MODE 3 (OUT): write Cf fp32 row-major + bias
// N-tile (128) == head width, so h = blockIdx.x.
// ---------------------------------------------------------------------------
template <int MODE>
__global__ __launch_bounds__(256) void gemm_proj(const u16* __restrict__ A,
                                                 const u16* __restrict__ B,
                                                 const float* __restrict__ bias,
                                                 const float* __restrict__ kn,
                                                 float* __restrict__ Cf,
                                                 u16* __restrict__ Ct,
                                                 u16* __restrict__ Cr) {
    __shared__ u16 As[128 * 32];
    __shared__ u16 Bs[128 * 32];
    const int tid = threadIdx.x;
    const int m0 = blockIdx.y * 128, n0 = blockIdx.x * 128;
    const int wave = tid >> 6, lane = tid & 63;
    const int wm = (wave >> 1) * 64, wn = (wave & 1) * 64;
    const int fr = lane & 15, kq = lane >> 4;
    const int srow = tid >> 2, scol = (tid & 3) * 8;

    floatx4 acc[4][4] = {};
    const size_t aOff0 = (size_t)(m0 + srow) * DIM + scol;
    const size_t aOff1 = (size_t)(m0 + 64 + srow) * DIM + scol;
    const size_t bOff0 = (size_t)(n0 + srow) * DIM + scol;
    const size_t bOff1 = (size_t)(n0 + 64 + srow) * DIM + scol;
    u16* lA0 = As + tid * 8;          u16* lA1 = As + (256 + tid) * 8;
    u16* lB0 = Bs + tid * 8;          u16* lB1 = Bs + (256 + tid) * 8;

    for (int kt = 0; kt < DIM; kt += 32) {
        GLOAD_LDS16(A + aOff0 + kt, lA0);
        GLOAD_LDS16(A + aOff1 + kt, lA1);
        GLOAD_LDS16(B + bOff0 + kt, lB0);
        GLOAD_LDS16(B + bOff1 + kt, lB1);
        __syncthreads();
        short8 af[4], bf[4];
#pragma unroll
        for (int i = 0; i < 4; i++)
            af[i] = *(const short8*)&As[(wm + i * 16 + fr) * 32 + kq * 8];
#pragma unroll
        for (int j = 0; j < 4; j++)
            bf[j] = *(const short8*)&Bs[(wn + j * 16 + fr) * 32 + kq * 8];
#pragma unroll
        for (int i = 0; i < 4; i++)
#pragma unroll
            for (int j = 0; j < 4; j++)
                acc[i][j] = __builtin_amdgcn_mfma_f32_16x16x32_bf16(af[i], bf[j], acc[i][j], 0, 0, 0);
        __syncthreads();
    }

    const int h = n0 >> 7;
#pragma unroll
    for (int i = 0; i < 4; i++) {
        const int rbase = m0 + wm + i * 16 + kq * 4;
        float rk[4];
        if (MODE == 2) {
#pragma unroll
            for (int r = 0; r < 4; r++) rk[r] = 1.0f / kn[(size_t)h * R + rbase + r];
        }
#pragma unroll
        for (int j = 0; j < 4; j++) {
            const int cl = wn + j * 16 + fr;        // 0..127 local col (= d within head)
            if (MODE == 3) {
                float badd = bias[n0 + cl];
#pragma unroll
                for (int r = 0; r < 4; r++)
                    Cf[(size_t)(rbase + r) * DIM + n0 + cl] = acc[i][j][r] + badd;
            } else {
                ushort4 pk;
                float v0 = acc[i][j][0], v1 = acc[i][j][1], v2 = acc[i][j][2], v3 = acc[i][j][3];
                if (MODE == 2) { v0 *= rk[0]; v1 *= rk[1]; v2 *= rk[2]; v3 *= rk[3]; }
                pk.x = f2b(v0); pk.y = f2b(v1); pk.z = f2b(v2); pk.w = f2b(v3);
                *(ushort4*)(Ct + (size_t)(h * 128 + cl) * R + rbase) = pk;
                if (MODE == 0) {
                    Cr[(size_t)(rbase + 0) * DIM + n0 + cl] = pk.x;
                    Cr[(size_t)(rbase + 1) * DIM + n0 + cl] = pk.y;
                    Cr[(size_t)(rbase + 2) * DIM + n0 + cl] = pk.z;
                    Cr[(size_t)(rbase + 3) * DIM + n0 + cl] = pk.w;
                }
            }
        }
    }
}

// ---------------------------------------------------------------------------
// Per-(h,r) stats from transposed bf16 [h][d][r]: norm, mean(optional), ratio
// Coalesced: consecutive threads = consecutive r.
// ---------------------------------------------------------------------------
__global__ __launch_bounds__(256) void stats_b(const u16* __restrict__ fT,
                                               float* __restrict__ norm_o,
                                               float* __restrict__ mean_o,
                                               float* __restrict__ ratio_o) {
    int h = blockIdx.y;
    int r = blockIdx.x * 256 + threadIdx.x;
    const u16* base = fT + (size_t)h * D * R + r;
    float sum = 0.0f, sq = 0.0f;
    for (int d = 0; d < D; d++) {
        float v = b2f(base[(size_t)d * R]);
        sum += v; sq += v * v;
    }
    int hr = h * R + r;
    norm_o[hr] = sqrtf(sq);
    if (mean_o) mean_o[hr] = sum * (1.0f / D);
    float var = (sq - sum * sum * (1.0f / D)) * (1.0f / (D - 1));
    ratio_o[hr] = 2.0f * fminf(var, 1.0f) / (var + 1.0f);
}

// ---------------------------------------------------------------------------
// Column reductions from [h][d][r]: g[h,d]=colmean; WITH_U: u[h,d]=sum mu*f,
// s2[h]=sum mu^2 (dg==0 blocks). grid (16 dgroups, H).
// ---------------------------------------------------------------------------
template <int WITH_U>
__global__ __launch_bounds__(256) void colsum_b(const u16* __restrict__ fT,
                                                const float* __restrict__ mu,
                                                float* __restrict__ g,
                                                float* __restrict__ u,
                                                float* __restrict__ s2) {
    int dg = blockIdx.x, h = blockIdx.y, tid = threadIdx.x;
    __shared__ float r1[256], r2[256];
    for (int dd = 0; dd < 8; dd++) {
        int d = dg * 8 + dd;
        const u16* rowp = fT + (size_t)(h * D + d) * R;
        float s = 0.0f, su = 0.0f;
        for (int it = 0; it < 32; it++) {
            int r = it * 256 + tid;
            float v = b2f(rowp[r]);
            s += v;
            if (WITH_U) su += v * mu[h * R + r];
        }
        r1[tid] = s; if (WITH_U) r2[tid] = su;
        __syncthreads();
        for (int st = 128; st > 0; st >>= 1) {
            if (tid < st) { r1[tid] += r1[tid + st]; if (WITH_U) r2[tid] += r2[tid + st]; }
            __syncthreads();
        }
        if (tid == 0) { g[h * D + d] = r1[0] * (1.0f / R); if (WITH_U) u[h * D + d] = r2[0]; }
        __syncthreads();
    }
    if (WITH_U && dg == 0) {
        float t = 0.0f;
        for (int it = 0; it < 32; it++) {
            float m = mu[h * R + it * 256 + tid];
            t += m * m;
        }
        r1[tid] = t;
        __syncthreads();
        for (int st = 128; st > 0; st >>= 1) {
            if (tid < st) r1[tid] += r1[tid + st];
            __syncthreads();
        }
        if (tid == 0) s2[h] = r1[0];
    }
}

// ---------------------------------------------------------------------------
// Raw syrk partials: P[h][c][d][e] = sum_{r in chunk c} f[r,d]*f[r,e]
// from qT[h][d][r]. grid (16 chunks, H). Both operands from one LDS tile.
// ---------------------------------------------------------------------------
__global__ __launch_bounds__(256) void syrk_q(const u16* __restrict__ qT,
                                              float* __restrict__ P) {
    __shared__ u16 As[128 * 32];
    const int c = blockIdx.x, h = blockIdx.y;
    const int tid = threadIdx.x;
    const int wave = tid >> 6, lane = tid & 63;
    const int wm = (wave >> 1) * 64, wn = (wave & 1) * 64;
    const int fr = lane & 15, kq = lane >> 4;
    const int srow = tid >> 2, scol = (tid & 3) * 8;
    floatx4 acc[4][4] = {};
    const size_t a0 = (size_t)(h * D + srow) * R + c * 512 + scol;
    const size_t a1 = (size_t)(h * D + 64 + srow) * R + c * 512 + scol;
    for (int kt = 0; kt < 512; kt += 32) {
        GLOAD_LDS16(qT + a0 + kt, As + tid * 8);
        GLOAD_LDS16(qT + a1 + kt, As + (256 + tid) * 8);
        __syncthreads();
        short8 af[4], bf[4];
#pragma unroll
        for (int i = 0; i < 4; i++)
            af[i] = *(const short8*)&As[(wm + i * 16 + fr) * 32 + kq * 8];
#pragma unroll
        for (int j = 0; j < 4; j++)
            bf[j] = *(const short8*)&As[(wn + j * 16 + fr) * 32 + kq * 8];
#pragma unroll
        for (int i = 0; i < 4; i++)
#pragma unroll
            for (int j = 0; j < 4; j++)
                acc[i][j] = __builtin_amdgcn_mfma_f32_16x16x32_bf16(af[i], bf[j], acc[i][j], 0, 0, 0);
        __syncthreads();
    }
    float* base = P + (size_t)(h * 16 + c) * (D * D);
#pragma unroll
    for (int i = 0; i < 4; i++) {
        int dr = wm + i * 16 + kq * 4;
#pragma unroll
        for (int j = 0; j < 4; j++) {
            int ec = wn + j * 16 + fr;
#pragma unroll
            for (int r = 0; r < 4; r++)
                base[(size_t)(dr + r) * D + ec] = acc[i][j][r];
        }
    }
}

// ---------------------------------------------------------------------------
__global__ __launch_bounds__(256) void reduce_fc(const float* __restrict__ P,
                                                 float* __restrict__ fc) {
    int idx = blockIdx.x * 256 + threadIdx.x;   // 0..131071
    int h = idx >> 14, de = idx & 16383;
    float s = 0.0f;
    for (int c = 0; c < 16; c++)
        s += P[(size_t)(h * 16 + c) * (D * D) + de];
    fc[idx] = s;
}

// ---------------------------------------------------------------------------
// Per-head decorr (from raw G + centering correction) + predictor MLP
// ---------------------------------------------------------------------------
__global__ __launch_bounds__(256) void head_kernel(const float* __restrict__ fc,
                                                   const float* __restrict__ ubuf,
                                                   const float* __restrict__ s2b,
                                                   const float* __restrict__ qg,
                                                   const float* __restrict__ kg,
                                                   const float* __restrict__ w1,
                                                   const float* __restrict__ b1,
                                                   const float* __restrict__ lng,
                                                   const float* __restrict__ lnb,
                                                   const float* __restrict__ w2,
                                                   const float* __restrict__ b2,
                                                   float* __restrict__ coef) {
    int h = blockIdx.x, tid = threadIdx.x;
    __shared__ float s1[256], s2[256], s3[256];
    __shared__ float feats[256];
    float s2h = s2b[h];
    float S = 0.0f;
    for (int idx = tid; idx < D * D; idx += 256) {
        int dd = idx >> 7, ee = idx & 127;
        if (dd != ee) {
            float vv = (fc[h * (D * D) + idx] - ubuf[h * D + dd] - ubuf[h * D + ee] + s2h) * (1.0f / R);
            S += vv * vv;
        }
    }
    s1[tid] = S;
    __syncthreads();
    for (int s = 128; s > 0; s >>= 1) {
        if (tid < s) s1[tid] += s1[tid + s];
        __syncthreads();
    }
    float dscale = expf(-5.0f * sqrtf(s1[0]) / (float)(D * D));
    __syncthreads();
    feats[tid] = (tid < 128) ? qg[h * D + tid] : kg[h * D + tid - 128];
    __syncthreads();
    float yv = 0.0f;
    if (tid < 128) {
        float a = b1[tid];
        for (int i = 0; i < 256; i++) a = fmaf(feats[i], w1[tid * 256 + i], a);
        yv = a;
    }
    s1[tid] = (tid < 128) ? yv : 0.0f;
    s2[tid] = (tid < 128) ? yv * yv : 0.0f;
    __syncthreads();
    for (int s = 128; s > 0; s >>= 1) {
        if (tid < s) { s1[tid] += s1[tid + s]; s2[tid] += s2[tid + s]; }
        __syncthreads();
    }
    float mean = s1[0] * (1.0f / 128.0f);
    float var = s2[0] * (1.0f / 128.0f) - mean * mean;
    float rstd = rsqrtf(var + 1e-5f);
    float rel = 0.0f;
    if (tid < 128)
        rel = fmaxf((yv - mean) * rstd * lng[tid] + lnb[tid], 0.0f);
    __syncthreads();
    s1[tid] = (tid < 128) ? rel * w2[0 * 128 + tid] : 0.0f;
    s2[tid] = (tid < 128) ? rel * w2[1 * 128 + tid] : 0.0f;
    s3[tid] = (tid < 128) ? rel * w2[2 * 128 + tid] : 0.0f;
    __syncthreads();
    for (int s = 128; s > 0; s >>= 1) {
        if (tid < s) { s1[tid] += s1[tid + s]; s2[tid] += s2[tid + s]; s3[tid] += s3[tid + s]; }
        __syncthreads();
    }
    if (tid == 0) {
        float g0 = s1[0] + b2[0], g1 = s2[0] + b2[1], g2 = s3[0] + b2[2];
        float mx = fmaxf(g0, fmaxf(g1, g2));
        float e0 = expf(g0 - mx), e1 = expf(g1 - mx), e2 = expf(g2 - mx);
        float inv = 1.0f / (e0 + e1 + e2);
        coef[h * 2 + 0] = e0 * inv + e1 * inv * dscale;  // cw + vw*decorr_scale
        coef[h * 2 + 1] = e2 * inv;                      // ww
    }
}

// ---------------------------------------------------------------------------
// Mt[h][qi][e][d] = sum_m V'[m,e] * K[m,d]  (bf16 MFMA), plus
// sv[h,qi,e] = sum_m kr[m]*kn[m]*V'[m,e] folded into the staging loop.
// ---------------------------------------------------------------------------
__global__ __launch_bounds__(256) void ktv_mfma(const u16* __restrict__ kT,
                                                const u16* __restrict__ vT,
                                                const float* __restrict__ kn,
                                                const float* __restrict__ kr,
                                                u16* __restrict__ Mt,
                                                float* __restrict__ sv) {
    __shared__ u16 As[128 * 32];
    __shared__ u16 Bs[128 * 32];
    __shared__ float wbuf[32];
    __shared__ float svred[256];
    const int qi = blockIdx.x, h = blockIdx.y;
    const int tid = threadIdx.x;
    const int wave = tid >> 6, lane = tid & 63;
    const int wm = (wave >> 1) * 64, wn = (wave & 1) * 64;
    const int fr = lane & 15, kq = lane >> 4;
    const int srow = tid >> 2, scol = (tid & 3) * 8;
    const int m0g = qi * 512;
    const size_t a0 = (size_t)(h * D + srow) * R + m0g + scol;
    const size_t a1 = (size_t)(h * D + 64 + srow) * R + m0g + scol;
    const int e_id = tid & 127, eh = tid >> 7;
    float svacc = 0.0f;
    floatx4 acc[4][4] = {};
    for (int kt = 0; kt < 512; kt += 32) {
        GLOAD_LDS16(vT + a0 + kt, As + tid * 8);
        GLOAD_LDS16(vT + a1 + kt, As + (256 + tid) * 8);
        GLOAD_LDS16(kT + a0 + kt, Bs + tid * 8);
        GLOAD_LDS16(kT + a1 + kt, Bs + (256 + tid) * 8);
        if (tid < 32) {
            int m = m0g + kt + tid;
            wbuf[tid] = kr[(size_t)h * R + m] * kn[(size_t)h * R + m];
        }
        __syncthreads();
        short8 af[4], bf[4];
#pragma unroll
        for (int i = 0; i < 4; i++)
            af[i] = *(const short8*)&As[(wm + i * 16 + fr) * 32 + kq * 8];
#pragma unroll
        for (int j = 0; j < 4; j++)
            bf[j] = *(const short8*)&Bs[(wn + j * 16 + fr) * 32 + kq * 8];
#pragma unroll
        for (int i = 0; i < 4; i++)
#pragma unroll
            for (int j = 0; j < 4; j++)
                acc[i][j] = __builtin_amdgcn_mfma_f32_16x16x32_bf16(af[i], bf[j], acc[i][j], 0, 0, 0);
        // sv partial from staged V' tile
#pragma unroll
        for (int jm = 0; jm < 16; jm++) {
            int mm = eh * 16 + jm;
            svacc += b2f(As[e_id * 32 + mm]) * wbuf[mm];
        }
        __syncthreads();
    }
    u16* mb = Mt + (size_t)(h * QB + qi) * D * D;
#pragma unroll
    for (int i = 0; i < 4; i++) {
        int er = wm + i * 16 + kq * 4;
#pragma unroll
        for (int j = 0; j < 4; j++) {
            int dc = wn + j * 16 + fr;
#pragma unroll
            for (int r = 0; r < 4; r++)
                mb[(size_t)(er + r) * D + dc] = f2b(acc[i][j][r]);
        }
    }
    svred[tid] = svacc;
    __syncthreads();
    if (tid < 128)
        sv[(size_t)(h * QB + qi) * D + tid] = svred[tid] + svred[tid + 128];
}

// ---------------------------------------------------------------------------
// attn: out[n,e] = sc1[n]*(sum_d fq[n,d]*Mt[e,d]) + sc2[n]*sv[e]  -> bf16
// grid (4 n-chunks, QB, H); K=128.
// ---------------------------------------------------------------------------
__global__ __launch_bounds__(256) void attn_mfma(const u16* __restrict__ fqb,
                                                 const u16* __restrict__ Mt,
                                                 const float* __restrict__ qn,
                                                 const float* __restrict__ qr,
                                                 const float* __restrict__ sv,
                                                 const float* __restrict__ coef,
                                                 u16* __restrict__ outb) {
    __shared__ u16 As[128 * 32];
    __shared__ u16 Bs[128 * 32];
    const int nb = blockIdx.x, qi = blockIdx.y, h = blockIdx.z;
    const int tid = threadIdx.x;
    const int wave = tid >> 6, lane = tid & 63;
    const int wm = (wave >> 1) * 64, wn = (wave & 1) * 64;
    const int fr = lane & 15, kq = lane >> 4;
    const int srow = tid >> 2, scol = (tid & 3) * 8;
    const int n0g = qi * 512 + nb * 128;
    const size_t a0 = (size_t)(n0g + srow) * DIM + h * D + scol;
    const size_t a1 = (size_t)(n0g + 64 + srow) * DIM + h * D + scol;
    const u16* mtb = Mt + (size_t)(h * QB + qi) * D * D;
    floatx4 acc[4][4] = {};
    for (int kt = 0; kt < 128; kt += 32) {
        GLOAD_LDS16(fqb + a0 + kt, As + tid * 8);
        GLOAD_LDS16(fqb + a1 + kt, As + (256 + tid) * 8);
        GLOAD_LDS16(mtb + (size_t)srow * D + kt + scol, Bs + tid * 8);
        GLOAD_LDS16(mtb + (size_t)(64 + srow) * D + kt + scol, Bs + (256 + tid) * 8);
        __syncthreads();
        short8 af[4], bf[4];
#pragma unroll
        for (int i = 0; i < 4; i++)
            af[i] = *(const short8*)&As[(wm + i * 16 + fr) * 32 + kq * 8];
#pragma unroll
        for (int j = 0; j < 4; j++)
            bf[j] = *(const short8*)&Bs[(wn + j * 16 + fr) * 32 + kq * 8];
#pragma unroll
        for (int i = 0; i < 4; i++)
#pragma unroll
            for (int j = 0; j < 4; j++)
                acc[i][j] = __builtin_amdgcn_mfma_f32_16x16x32_bf16(af[i], bf[j], acc[i][j], 0, 0, 0);
        __syncthreads();
    }
    float c0 = coef[2 * h], c1 = coef[2 * h + 1];
#pragma unroll
    for (int i = 0; i < 4; i++) {
        int nr = n0g + wm + i * 16 + kq * 4;   // global row in [0,8192)
        float sc1[4], sc2[4];
#pragma unroll
        for (int r = 0; r < 4; r++) {
            sc1[r] = c0 / qn[(size_t)h * R + nr + r];
            sc2[r] = c1 * qr[(size_t)h * R + nr + r];
        }
#pragma unroll
        for (int j = 0; j < 4; j++) {
            int ec = wn + j * 16 + fr;
            float svv = sv[(size_t)(h * QB + qi) * D + ec];
#pragma unroll
            for (int r = 0; r < 4; r++)
                outb[(size_t)(nr + r) * DIM + h * D + ec] = f2b(sc1[r] * acc[i][j][r] + sc2[r] * svv);
        }
    }
}

// ---------------------------------------------------------------------------
extern "C" void kernel_launch(void* const* d_in, const int* in_sizes, int n_in,
                              void* d_out, int out_size, void* d_ws, size_t ws_size,
                              hipStream_t stream) {
    (void)in_sizes; (void)n_in; (void)out_size; (void)ws_size;
    const float* q      = (const float*)d_in[0];
    const float* k      = (const float*)d_in[1];
    const float* v      = (const float*)d_in[2];
    const float* ln_g   = (const float*)d_in[3];
    const float* ln_b   = (const float*)d_in[4];
    const float* w_in   = (const float*)d_in[5];
    const float* wp_w1  = (const float*)d_in[6];
    const float* wp_b1  = (const float*)d_in[7];
    const float* wp_lng = (const float*)d_in[8];
    const float* wp_lnb = (const float*)d_in[9];
    const float* wp_w2  = (const float*)d_in[10];
    const float* wp_b2  = (const float*)d_in[11];
    const float* w_out  = (const float*)d_in[12];
    const float* b_out  = (const float*)d_in[13];
    float* out = (float*)d_out;

    constexpr size_t F = (size_t)R * DIM;     // 8,388,608 elements
    u16* xb16    = (u16*)d_ws;                // LN out / attn out (row-major)
    u16* fqb     = xb16 + F;                  // f_q row-major bf16
    u16* qT      = fqb + F;                   // [h][d][r]
    u16* kT      = qT + F;
    u16* vT      = kT + F;                    // V' = V/kn
    u16* w_in16  = vT + F;                    // 1,048,576
    u16* w_out16 = w_in16 + (size_t)DIM * DIM;
    u16* Mt      = w_out16 + (size_t)DIM * DIM;   // H*QB*D*D = 2,097,152
    float* fp    = (float*)(Mt + (size_t)H * QB * D * D);
    float* P     = fp;                        // syrk partials 16*H*D*D = 2,097,152
    float* fc    = P + (size_t)16 * H * D * D;
    float* qn    = fc + (size_t)H * D * D;
    float* qm    = qn + (size_t)H * R;
    float* qr    = qm + (size_t)H * R;
    float* kn    = qr + (size_t)H * R;
    float* kr    = kn + (size_t)H * R;
    float* qg    = kr + (size_t)H * R;        // H*D
    float* kg    = qg + H * D;
    float* ubuf  = kg + H * D;
    float* s2    = ubuf + H * D;              // H
    float* coef  = s2 + H;                    // 16
    float* svb   = coef + 16;                 // H*QB*D

    dim3 gemmGrid(DIM / 128, R / 128);        // (8, 64)

    cvt_kernel<<<1024, 256, 0, stream>>>(w_in, w_in16, DIM * DIM / 4);
    cvt_kernel<<<1024, 256, 0, stream>>>(w_out, w_out16, DIM * DIM / 4);

    ln_kernel<<<R, 256, 0, stream>>>(q, ln_g, ln_b, xb16);
    gemm_proj<0><<<gemmGrid, 256, 0, stream>>>(xb16, w_in16, nullptr, nullptr, nullptr, qT, fqb);
    ln_kernel<<<R, 256, 0, stream>>>(k, ln_g, ln_b, xb16);
    gemm_proj<1><<<gemmGrid, 256, 0, stream>>>(xb16, w_in16, nullptr, nullptr, nullptr, kT, nullptr);
    stats_b<<<dim3(32, H), 256, 0, stream>>>(kT, kn, nullptr, kr);
    ln_kernel<<<R, 256, 0, stream>>>(v, ln_g, ln_b, xb16);
    gemm_proj<2><<<gemmGrid, 256, 0, stream>>>(xb16, w_in16, nullptr, kn, nullptr, vT, nullptr);

    stats_b<<<dim3(32, H), 256, 0, stream>>>(qT, qn, qm, qr);
    colsum_b<1><<<dim3(16, H), 256, 0, stream>>>(qT, qm, qg, ubuf, s2);
    colsum_b<0><<<dim3(16, H), 256, 0, stream>>>(kT, nullptr, kg, nullptr, nullptr);

    syrk_q<<<dim3(16, H), 256, 0, stream>>>(qT, P);
    reduce_fc<<<512, 256, 0, stream>>>(P, fc);

    head_kernel<<<H, 256, 0, stream>>>(fc, ubuf, s2, qg, kg, wp_w1, wp_b1,
                                       wp_lng, wp_lnb, wp_w2, wp_b2, coef);

    ktv_mfma<<<dim3(QB, H), 256, 0, stream>>>(kT, vT, kn, kr, Mt, svb);

    attn_mfma<<<dim3(4, QB, H), 256, 0, stream>>>(fqb, Mt, qn, qr, svb, coef, xb16);

    gemm_proj<3><<<gemmGrid, 256, 0, stream>>>(xb16, w_out16, b_out, nullptr, out, nullptr, nullptr);
}

// Round 4
// 391.613 us; speedup vs baseline: 3.6666x; 1.0495x over previous
//
#include <hip/hip_runtime.h>
#include <hip/hip_bf16.h>

typedef unsigned short u16;
typedef __attribute__((ext_vector_type(8))) short short8;
typedef __attribute__((ext_vector_type(4))) float floatx4;

#define H 8
#define D 128
#define DIM 1024
#define QB 16
#define NSEQ 512
#define R 8192            /* QB*NSEQ rows */

__device__ inline u16 f2b(float x) {
    union { float f; unsigned int u; } c{x};
    unsigned int lsb = (c.u >> 16) & 1;
    unsigned int r = c.u + 0x7fffu + lsb;   // round-to-nearest-even
    return (u16)(r >> 16);
}
__device__ inline float b2f(u16 u) {
    union { unsigned int i; float f; } c;
    c.i = (unsigned int)u << 16;
    return c.f;
}

#define GLOAD_LDS16(gptr, lptr)                                                        \
    __builtin_amdgcn_global_load_lds(                                                  \
        (const __attribute__((address_space(1))) unsigned int*)(gptr),                 \
        (__attribute__((address_space(3))) unsigned int*)(lptr), 16, 0, 0)

// ---------------------------------------------------------------------------
// LayerNorm over DIM=1024 for q/k/v stacked: grid (R, 3) -> lnall[3R][DIM]
// ---------------------------------------------------------------------------
__global__ __launch_bounds__(256) void ln_all(const float* __restrict__ q,
                                              const float* __restrict__ k,
                                              const float* __restrict__ v,
                                              const float* __restrict__ g,
                                              const float* __restrict__ b,
                                              u16* __restrict__ out) {
    const float* src = (blockIdx.y == 0) ? q : (blockIdx.y == 1) ? k : v;
    int r = blockIdx.x;
    int tid = threadIdx.x;
    const float* row = src + (size_t)r * DIM;
    float4 vv = *(const float4*)(row + tid * 4);
    float sum = vv.x + vv.y + vv.z + vv.w;
    float sq = vv.x * vv.x + vv.y * vv.y + vv.z * vv.z + vv.w * vv.w;
    __shared__ float s1[256], s2[256];
    s1[tid] = sum; s2[tid] = sq;
    __syncthreads();
    for (int s = 128; s > 0; s >>= 1) {
        if (tid < s) { s1[tid] += s1[tid + s]; s2[tid] += s2[tid + s]; }
        __syncthreads();
    }
    float mean = s1[0] * (1.0f / DIM);
    float var = s2[0] * (1.0f / DIM) - mean * mean;
    float rstd = rsqrtf(var + 1e-5f);
    float4 gv = *(const float4*)(g + tid * 4);
    float4 bv = *(const float4*)(b + tid * 4);
    ushort4 pk;
    pk.x = f2b((vv.x - mean) * rstd * gv.x + bv.x);
    pk.y = f2b((vv.y - mean) * rstd * gv.y + bv.y);
    pk.z = f2b((vv.z - mean) * rstd * gv.z + bv.z);
    pk.w = f2b((vv.w - mean) * rstd * gv.w + bv.w);
    *(ushort4*)(out + ((size_t)blockIdx.y * R + r) * DIM + tid * 4) = pk;
}

// ---------------------------------------------------------------------------
// Both weight matrices -> bf16 in one dispatch
// ---------------------------------------------------------------------------
__global__ __launch_bounds__(256) void cvt2_kernel(const float* __restrict__ a,
                                                   const float* __restrict__ b,
                                                   u16* __restrict__ oa,
                                                   u16* __restrict__ ob, int n4each) {
    int i = blockIdx.x * 256 + threadIdx.x;
    const float* src; u16* dst; int j;
    if (i < n4each) { src = a; dst = oa; j = i; }
    else            { src = b; dst = ob; j = i - n4each; }
    float4 v = *(const float4*)(src + (size_t)j * 4);
    ushort4 pk;
    pk.x = f2b(v.x); pk.y = f2b(v.y); pk.z = f2b(v.z); pk.w = f2b(v.w);
    *(ushort4*)(dst + (size_t)j * 4) = pk;
}

// ---------------------------------------------------------------------------
// Stacked QKV projection: A=lnall[3R,1024] @ w_in^T, 128x128 tile, BK=32.
// Segment (blockIdx.y>>6): 0=Q -> qT + fqb + (qn,qm,qr); 1=K -> kTh=K/||k||
// + (kn,kr); 2=V -> vT plain. N-tile == head => full feature row in-block:
// per-row stats via shuffle+LDS reduction over the accumulators (fp32-exact).
// ---------------------------------------------------------------------------
__global__ __launch_bounds__(256) void gemm_qkv(const u16* __restrict__ A,
                                                const u16* __restrict__ B,
                                                u16* __restrict__ qT,
                                                u16* __restrict__ fqb,
                                                u16* __restrict__ kTh,
                                                u16* __restrict__ vT,
                                                float* __restrict__ qn,
                                                float* __restrict__ qm,
                                                float* __restrict__ qr,
                                                float* __restrict__ kn,
                                                float* __restrict__ kr) {
    __shared__ u16 As[128 * 32];
    __shared__ u16 Bs[128 * 32];
    const int tid = threadIdx.x;
    const int m0 = blockIdx.y * 128, n0 = blockIdx.x * 128;
    const int wave = tid >> 6, lane = tid & 63;
    const int wm = (wave >> 1) * 64, wn = (wave & 1) * 64;
    const int fr = lane & 15, kq = lane >> 4;
    const int srow = tid >> 2, scol = (tid & 3) * 8;

    floatx4 acc[4][4] = {};
    const size_t aOff0 = (size_t)(m0 + srow) * DIM + scol;
    const size_t aOff1 = (size_t)(m0 + 64 + srow) * DIM + scol;
    const size_t bOff0 = (size_t)(n0 + srow) * DIM + scol;
    const size_t bOff1 = (size_t)(n0 + 64 + srow) * DIM + scol;

    for (int kt = 0; kt < DIM; kt += 32) {
        GLOAD_LDS16(A + aOff0 + kt, As + tid * 8);
        GLOAD_LDS16(A + aOff1 + kt, As + (256 + tid) * 8);
        GLOAD_LDS16(B + bOff0 + kt, Bs + tid * 8);
        GLOAD_LDS16(B + bOff1 + kt, Bs + (256 + tid) * 8);
        __syncthreads();
        short8 af[4], bf[4];
#pragma unroll
        for (int i = 0; i < 4; i++)
            af[i] = *(const short8*)&As[(wm + i * 16 + fr) * 32 + kq * 8];
#pragma unroll
        for (int j = 0; j < 4; j++)
            bf[j] = *(const short8*)&Bs[(wn + j * 16 + fr) * 32 + kq * 8];
#pragma unroll
        for (int i = 0; i < 4; i++)
#pragma unroll
            for (int j = 0; j < 4; j++)
                acc[i][j] = __builtin_amdgcn_mfma_f32_16x16x32_bf16(af[i], bf[j], acc[i][j], 0, 0, 0);
        __syncthreads();
    }

    const int seg = blockIdx.y >> 6;               // 0=Q 1=K 2=V (64 row-blocks each)
    const int lrb = (blockIdx.y & 63) * 128;       // segment-local row base
    const int h = blockIdx.x;
    float* sred = (float*)As;                      // [128][2 halves][2]{sum,sq}
    float* invb = (float*)Bs;                      // [128] 1/||k|| (seg 1)

    if (seg <= 1) {
        const int half = wn >> 6;
#pragma unroll
        for (int i = 0; i < 4; i++) {
            float s[4] = {}, qs[4] = {};
#pragma unroll
            for (int j = 0; j < 4; j++)
#pragma unroll
                for (int r = 0; r < 4; r++) {
                    float vv = acc[i][j][r];
                    s[r] += vv; qs[r] += vv * vv;
                }
#pragma unroll
            for (int m = 1; m < 16; m <<= 1)
#pragma unroll
                for (int r = 0; r < 4; r++) {
                    s[r] += __shfl_xor(s[r], m);
                    qs[r] += __shfl_xor(qs[r], m);
                }
            if (fr == 0) {
                int row = wm + i * 16 + kq * 4;
#pragma unroll
                for (int r = 0; r < 4; r++) {
                    sred[(row + r) * 4 + half * 2 + 0] = s[r];
                    sred[(row + r) * 4 + half * 2 + 1] = qs[r];
                }
            }
        }
        __syncthreads();
        if (tid < 128) {
            float sum = sred[tid * 4 + 0] + sred[tid * 4 + 2];
            float sq  = sred[tid * 4 + 1] + sred[tid * 4 + 3];
            float nrm = sqrtf(sq);
            float var = (sq - sum * sum * (1.0f / D)) * (1.0f / (D - 1));
            float ratio = 2.0f * fminf(var, 1.0f) / (var + 1.0f);
            size_t idx = (size_t)h * R + lrb + tid;
            if (seg == 0) {
                qn[idx] = nrm; qm[idx] = sum * (1.0f / D); qr[idx] = ratio;
            } else {
                kn[idx] = nrm; kr[idx] = ratio;
                invb[tid] = 1.0f / nrm;
            }
        }
        __syncthreads();
    }

    u16* dstT = (seg == 0) ? qT : (seg == 1) ? kTh : vT;
#pragma unroll
    for (int i = 0; i < 4; i++) {
        const int tr = wm + i * 16 + kq * 4;       // tile row base (0..127)
        const int lrow = lrb + tr;                 // segment-local row base
        float sc[4] = {1.0f, 1.0f, 1.0f, 1.0f};
        if (seg == 1) {
#pragma unroll
            for (int r = 0; r < 4; r++) sc[r] = invb[tr + r];
        }
#pragma unroll
        for (int j = 0; j < 4; j++) {
            const int cl = wn + j * 16 + fr;       // head-local col (d)
            ushort4 pk;
            pk.x = f2b(acc[i][j][0] * sc[0]);
            pk.y = f2b(acc[i][j][1] * sc[1]);
            pk.z = f2b(acc[i][j][2] * sc[2]);
            pk.w = f2b(acc[i][j][3] * sc[3]);
            *(ushort4*)(dstT + (size_t)(h * D + cl) * R + lrow) = pk;
            if (seg == 0) {
                fqb[(size_t)(lrow + 0) * DIM + h * D + cl] = pk.x;
                fqb[(size_t)(lrow + 1) * DIM + h * D + cl] = pk.y;
                fqb[(size_t)(lrow + 2) * DIM + h * D + cl] = pk.z;
                fqb[(size_t)(lrow + 3) * DIM + h * D + cl] = pk.w;
            }
        }
    }
}

// ---------------------------------------------------------------------------
// Column reductions from [h][d][r].
// MODE 1 (Q): g=colmean, u=sum mu*f, s2[h]=sum mu^2 (dg==0 blocks)
// MODE 2 (K-hat): g = (1/R) sum f*kn[r]   (recovers raw-K colmean)
// ---------------------------------------------------------------------------
template <int MODE>
__global__ __launch_bounds__(256) void colsum_b(const u16* __restrict__ fT,
                                                const float* __restrict__ wvec,
                                                float* __restrict__ g,
                                                float* __restrict__ u,
                                                float* __restrict__ s2) {
    int dg = blockIdx.x, h = blockIdx.y, tid = threadIdx.x;
    __shared__ float r1[256], r2[256];
    for (int dd = 0; dd < 8; dd++) {
        int d = dg * 8 + dd;
        const u16* rowp = fT + (size_t)(h * D + d) * R;
        float s = 0.0f, su = 0.0f;
        for (int it = 0; it < 32; it++) {
            int r = it * 256 + tid;
            float v = b2f(rowp[r]);
            if (MODE == 2) s += v * wvec[h * R + r];
            else { s += v; su += v * wvec[h * R + r]; }
        }
        r1[tid] = s; r2[tid] = su;
        __syncthreads();
        for (int st = 128; st > 0; st >>= 1) {
            if (tid < st) { r1[tid] += r1[tid + st]; r2[tid] += r2[tid + st]; }
            __syncthreads();
        }
        if (tid == 0) {
            g[h * D + d] = r1[0] * (1.0f / R);
            if (MODE == 1) u[h * D + d] = r2[0];
        }
        __syncthreads();
    }
    if (MODE == 1 && dg == 0) {
        float t = 0.0f;
        for (int it = 0; it < 32; it++) {
            float m = wvec[h * R + it * 256 + tid];
            t += m * m;
        }
        r1[tid] = t;
        __syncthreads();
        for (int st = 128; st > 0; st >>= 1) {
            if (tid < st) r1[tid] += r1[tid + st];
            __syncthreads();
        }
        if (tid == 0) s2[h] = r1[0];
    }
}

// ---------------------------------------------------------------------------
// Raw syrk partials: P[h][c][d][e] = sum_{r in chunk c} f[r,d]*f[r,e]
// ---------------------------------------------------------------------------
__global__ __launch_bounds__(256) void syrk_q(const u16* __restrict__ qT,
                                              float* __restrict__ P) {
    __shared__ u16 As[128 * 32];
    const int c = blockIdx.x, h = blockIdx.y;
    const int tid = threadIdx.x;
    const int wave = tid >> 6, lane = tid & 63;
    const int wm = (wave >> 1) * 64, wn = (wave & 1) * 64;
    const int fr = lane & 15, kq = lane >> 4;
    const int srow = tid >> 2, scol = (tid & 3) * 8;
    floatx4 acc[4][4] = {};
    const size_t a0 = (size_t)(h * D + srow) * R + c * 512 + scol;
    const size_t a1 = (size_t)(h * D + 64 + srow) * R + c * 512 + scol;
    for (int kt = 0; kt < 512; kt += 32) {
        GLOAD_LDS16(qT + a0 + kt, As + tid * 8);
        GLOAD_LDS16(qT + a1 + kt, As + (256 + tid) * 8);
        __syncthreads();
        short8 af[4], bf[4];
#pragma unroll
        for (int i = 0; i < 4; i++)
            af[i] = *(const short8*)&As[(wm + i * 16 + fr) * 32 + kq * 8];
#pragma unroll
        for (int j = 0; j < 4; j++)
            bf[j] = *(const short8*)&As[(wn + j * 16 + fr) * 32 + kq * 8];
#pragma unroll
        for (int i = 0; i < 4; i++)
#pragma unroll
            for (int j = 0; j < 4; j++)
                acc[i][j] = __builtin_amdgcn_mfma_f32_16x16x32_bf16(af[i], bf[j], acc[i][j], 0, 0, 0);
        __syncthreads();
    }
    float* base = P + (size_t)(h * 16 + c) * (D * D);
#pragma unroll
    for (int i = 0; i < 4; i++) {
        int dr = wm + i * 16 + kq * 4;
#pragma unroll
        for (int j = 0; j < 4; j++) {
            int ec = wn + j * 16 + fr;
#pragma unroll
            for (int r = 0; r < 4; r++)
                base[(size_t)(dr + r) * D + ec] = acc[i][j][r];
        }
    }
}

// ---------------------------------------------------------------------------
__global__ __launch_bounds__(256) void reduce_fc(const float* __restrict__ P,
                                                 float* __restrict__ fc) {
    int idx = blockIdx.x * 256 + threadIdx.x;   // 0..131071
    int h = idx >> 14, de = idx & 16383;
    float s = 0.0f;
    for (int c = 0; c < 16; c++)
        s += P[(size_t)(h * 16 + c) * (D * D) + de];
    fc[idx] = s;
}

// ---------------------------------------------------------------------------
// Per-head decorr (raw G + centering correction) + predictor MLP
// ---------------------------------------------------------------------------
__global__ __launch_bounds__(256) void head_kernel(const float* __restrict__ fc,
                                                   const float* __restrict__ ubuf,
                                                   const float* __restrict__ s2b,
                                                   const float* __restrict__ qg,
                                                   const float* __restrict__ kg,
                                                   const float* __restrict__ w1,
                                                   const float* __restrict__ b1,
                                                   const float* __restrict__ lng,
                                                   const float* __restrict__ lnb,
                                                   const float* __restrict__ w2,
                                                   const float* __restrict__ b2,
                                                   float* __restrict__ coef) {
    int h = blockIdx.x, tid = threadIdx.x;
    __shared__ float s1[256], s2[256], s3[256];
    __shared__ float feats[256];
    float s2h = s2b[h];
    float S = 0.0f;
    for (int idx = tid; idx < D * D; idx += 256) {
        int dd = idx >> 7, ee = idx & 127;
        if (dd != ee) {
            float vv = (fc[h * (D * D) + idx] - ubuf[h * D + dd] - ubuf[h * D + ee] + s2h) * (1.0f / R);
            S += vv * vv;
        }
    }
    s1[tid] = S;
    __syncthreads();
    for (int s = 128; s > 0; s >>= 1) {
        if (tid < s) s1[tid] += s1[tid + s];
        __syncthreads();
    }
    float dscale = expf(-5.0f * sqrtf(s1[0]) / (float)(D * D));
    __syncthreads();
    feats[tid] = (tid < 128) ? qg[h * D + tid] : kg[h * D + tid - 128];
    __syncthreads();
    float yv = 0.0f;
    if (tid < 128) {
        float a = b1[tid];
        for (int i = 0; i < 256; i++) a = fmaf(feats[i], w1[tid * 256 + i], a);
        yv = a;
    }
    s1[tid] = (tid < 128) ? yv : 0.0f;
    s2[tid] = (tid < 128) ? yv * yv : 0.0f;
    __syncthreads();
    for (int s = 128; s > 0; s >>= 1) {
        if (tid < s) { s1[tid] += s1[tid + s]; s2[tid] += s2[tid + s]; }
        __syncthreads();
    }
    float mean = s1[0] * (1.0f / 128.0f);
    float var = s2[0] * (1.0f / 128.0f) - mean * mean;
    float rstd = rsqrtf(var + 1e-5f);
    float rel = 0.0f;
    if (tid < 128)
        rel = fmaxf((yv - mean) * rstd * lng[tid] + lnb[tid], 0.0f);
    __syncthreads();
    s1[tid] = (tid < 128) ? rel * w2[0 * 128 + tid] : 0.0f;
    s2[tid] = (tid < 128) ? rel * w2[1 * 128 + tid] : 0.0f;
    s3[tid] = (tid < 128) ? rel * w2[2 * 128 + tid] : 0.0f;
    __syncthreads();
    for (int s = 128; s > 0; s >>= 1) {
        if (tid < s) { s1[tid] += s1[tid + s]; s2[tid] += s2[tid + s]; s3[tid] += s3[tid + s]; }
        __syncthreads();
    }
    if (tid == 0) {
        float g0 = s1[0] + b2[0], g1 = s2[0] + b2[1], g2 = s3[0] + b2[2];
        float mx = fmaxf(g0, fmaxf(g1, g2));
        float e0 = expf(g0 - mx), e1 = expf(g1 - mx), e2 = expf(g2 - mx);
        float inv = 1.0f / (e0 + e1 + e2);
        coef[h * 2 + 0] = e0 * inv + e1 * inv * dscale;  // cw + vw*decorr_scale
        coef[h * 2 + 1] = e2 * inv;                      // ww
    }
}

// ---------------------------------------------------------------------------
// Mt[h][qi][e][d] = sum_m V[m,e] * Khat[m,d]  (bf16 MFMA), plus
// sv[h,qi,e] = sum_m kr[m]*V[m,e] folded into the staging loop.
// ---------------------------------------------------------------------------
__global__ __launch_bounds__(256) void ktv_mfma(const u16* __restrict__ kTh,
                                                const u16* __restrict__ vT,
                                                const float* __restrict__ kr,
                                                u16* __restrict__ Mt,
                                                float* __restrict__ sv) {
    __shared__ u16 As[128 * 32];
    __shared__ u16 Bs[128 * 32];
    __shared__ float wbuf[32];
    __shared__ float svred[256];
    const int qi = blockIdx.x, h = blockIdx.y;
    const int tid = threadIdx.x;
    const int wave = tid >> 6, lane = tid & 63;
    const int wm = (wave >> 1) * 64, wn = (wave & 1) * 64;
    const int fr = lane & 15, kq = lane >> 4;
    const int srow = tid >> 2, scol = (tid & 3) * 8;
    const int m0g = qi * 512;
    const size_t a0 = (size_t)(h * D + srow) * R + m0g + scol;
    const size_t a1 = (size_t)(h * D + 64 + srow) * R + m0g + scol;
    const int e_id = tid & 127, eh = tid >> 7;
    float svacc = 0.0f;
    floatx4 acc[4][4] = {};
    for (int kt = 0; kt < 512; kt += 32) {
        GLOAD_LDS16(vT + a0 + kt, As + tid * 8);
        GLOAD_LDS16(vT + a1 + kt, As + (256 + tid) * 8);
        GLOAD_LDS16(kTh + a0 + kt, Bs + tid * 8);
        GLOAD_LDS16(kTh + a1 + kt, Bs + (256 + tid) * 8);
        if (tid < 32) wbuf[tid] = kr[(size_t)h * R + m0g + kt + tid];
        __syncthreads();
        short8 af[4], bf[4];
#pragma unroll
        for (int i = 0; i < 4; i++)
            af[i] = *(const short8*)&As[(wm + i * 16 + fr) * 32 + kq * 8];
#pragma unroll
        for (int j = 0; j < 4; j++)
            bf[j] = *(const short8*)&Bs[(wn + j * 16 + fr) * 32 + kq * 8];
#pragma unroll
        for (int i = 0; i < 4; i++)
#pragma unroll
            for (int j = 0; j < 4; j++)
                acc[i][j] = __builtin_amdgcn_mfma_f32_16x16x32_bf16(af[i], bf[j], acc[i][j], 0, 0, 0);
#pragma unroll
        for (int jm = 0; jm < 16; jm++) {
            int mm = eh * 16 + jm;
            svacc += b2f(As[e_id * 32 + mm]) * wbuf[mm];
        }
        __syncthreads();
    }
    u16* mb = Mt + (size_t)(h * QB + qi) * D * D;
#pragma unroll
    for (int i = 0; i < 4; i++) {
        int er = wm + i * 16 + kq * 4;
#pragma unroll
        for (int j = 0; j < 4; j++) {
            int dc = wn + j * 16 + fr;
#pragma unroll
            for (int r = 0; r < 4; r++)
                mb[(size_t)(er + r) * D + dc] = f2b(acc[i][j][r]);
        }
    }
    svred[tid] = svacc;
    __syncthreads();
    if (tid < 128)
        sv[(size_t)(h * QB + qi) * D + tid] = svred[tid] + svred[tid + 128];
}

// ---------------------------------------------------------------------------
// attn: out[n,e] = sc1[n]*(sum_d fq[n,d]*Mt[e,d]) + sc2[n]*sv[e]  -> bf16
// ---------------------------------------------------------------------------
__global__ __launch_bounds__(256) void attn_mfma(const u16* __restrict__ fqb,
                                                 const u16* __restrict__ Mt,
                                                 const float* __restrict__ qn,
                                                 const float* __restrict__ qr,
                                                 const float* __restrict__ sv,
                                                 const float* __restrict__ coef,
                                                 u16* __restrict__ outb) {
    __shared__ u16 As[128 * 32];
    __shared__ u16 Bs[128 * 32];
    const int nb = blockIdx.x, qi = blockIdx.y, h = blockIdx.z;
    const int tid = threadIdx.x;
    const int wave = tid >> 6, lane = tid & 63;
    const int wm = (wave >> 1) * 64, wn = (wave & 1) * 64;
    const int fr = lane & 15, kq = lane >> 4;
    const int srow = tid >> 2, scol = (tid & 3) * 8;
    const int n0g = qi * 512 + nb * 128;
    const size_t a0 = (size_t)(n0g + srow) * DIM + h * D + scol;
    const size_t a1 = (size_t)(n0g + 64 + srow) * DIM + h * D + scol;
    const u16* mtb = Mt + (size_t)(h * QB + qi) * D * D;
    floatx4 acc[4][4] = {};
    for (int kt = 0; kt < 128; kt += 32) {
        GLOAD_LDS16(fqb + a0 + kt, As + tid * 8);
        GLOAD_LDS16(fqb + a1 + kt, As + (256 + tid) * 8);
        GLOAD_LDS16(mtb + (size_t)srow * D + kt + scol, Bs + tid * 8);
        GLOAD_LDS16(mtb + (size_t)(64 + srow) * D + kt + scol, Bs + (256 + tid) * 8);
        __syncthreads();
        short8 af[4], bf[4];
#pragma unroll
        for (int i = 0; i < 4; i++)
            af[i] = *(const short8*)&As[(wm + i * 16 + fr) * 32 + kq * 8];
#pragma unroll
        for (int j = 0; j < 4; j++)
            bf[j] = *(const short8*)&Bs[(wn + j * 16 + fr) * 32 + kq * 8];
#pragma unroll
        for (int i = 0; i < 4; i++)
#pragma unroll
            for (int j = 0; j < 4; j++)
                acc[i][j] = __builtin_amdgcn_mfma_f32_16x16x32_bf16(af[i], bf[j], acc[i][j], 0, 0, 0);
        __syncthreads();
    }
    float c0 = coef[2 * h], c1 = coef[2 * h + 1];
#pragma unroll
    for (int i = 0; i < 4; i++) {
        int nr = n0g + wm + i * 16 + kq * 4;
        float sc1[4], sc2[4];
#pragma unroll
        for (int r = 0; r < 4; r++) {
            sc1[r] = c0 / qn[(size_t)h * R + nr + r];
            sc2[r] = c1 * qr[(size_t)h * R + nr + r];
        }
#pragma unroll
        for (int j = 0; j < 4; j++) {
            int ec = wn + j * 16 + fr;
            float svv = sv[(size_t)(h * QB + qi) * D + ec];
#pragma unroll
            for (int r = 0; r < 4; r++)
                outb[(size_t)(nr + r) * DIM + h * D + ec] = f2b(sc1[r] * acc[i][j][r] + sc2[r] * svv);
        }
    }
}

// ---------------------------------------------------------------------------
// Output GEMM: C = A[8192,1024] @ w_out^T + bias  (bf16 in, fp32 out)
// ---------------------------------------------------------------------------
__global__ __launch_bounds__(256) void gemm_out(const u16* __restrict__ A,
                                                const u16* __restrict__ B,
                                                const float* __restrict__ bias,
                                                float* __restrict__ C) {
    __shared__ u16 As[128 * 32];
    __shared__ u16 Bs[128 * 32];
    const int tid = threadIdx.x;
    const int m0 = blockIdx.y * 128, n0 = blockIdx.x * 128;
    const int wave = tid >> 6, lane = tid & 63;
    const int wm = (wave >> 1) * 64, wn = (wave & 1) * 64;
    const int fr = lane & 15, kq = lane >> 4;
    const int srow = tid >> 2, scol = (tid & 3) * 8;
    floatx4 acc[4][4] = {};
    const size_t aOff0 = (size_t)(m0 + srow) * DIM + scol;
    const size_t aOff1 = (size_t)(m0 + 64 + srow) * DIM + scol;
    const size_t bOff0 = (size_t)(n0 + srow) * DIM + scol;
    const size_t bOff1 = (size_t)(n0 + 64 + srow) * DIM + scol;
    for (int kt = 0; kt < DIM; kt += 32) {
        GLOAD_LDS16(A + aOff0 + kt, As + tid * 8);
        GLOAD_LDS16(A + aOff1 + kt, As + (256 + tid) * 8);
        GLOAD_LDS16(B + bOff0 + kt, Bs + tid * 8);
        GLOAD_LDS16(B + bOff1 + kt, Bs + (256 + tid) * 8);
        __syncthreads();
        short8 af[4], bf[4];
#pragma unroll
        for (int i = 0; i < 4; i++)
            af[i] = *(const short8*)&As[(wm + i * 16 + fr) * 32 + kq * 8];
#pragma unroll
        for (int j = 0; j < 4; j++)
            bf[j] = *(const short8*)&Bs[(wn + j * 16 + fr) * 32 + kq * 8];
#pragma unroll
        for (int i = 0; i < 4; i++)
#pragma unroll
            for (int j = 0; j < 4; j++)
                acc[i][j] = __builtin_amdgcn_mfma_f32_16x16x32_bf16(af[i], bf[j], acc[i][j], 0, 0, 0);
        __syncthreads();
    }
#pragma unroll
    for (int i = 0; i < 4; i++) {
        int rbase = m0 + wm + i * 16 + kq * 4;
#pragma unroll
        for (int j = 0; j < 4; j++) {
            int col = n0 + wn + j * 16 + fr;
            float badd = bias[col];
#pragma unroll
            for (int r = 0; r < 4; r++)
                C[(size_t)(rbase + r) * DIM + col] = acc[i][j][r] + badd;
        }
    }
}

// ---------------------------------------------------------------------------
extern "C" void kernel_launch(void* const* d_in, const int* in_sizes, int n_in,
                              void* d_out, int out_size, void* d_ws, size_t ws_size,
                              hipStream_t stream) {
    (void)in_sizes; (void)n_in; (void)out_size; (void)ws_size;
    const float* q      = (const float*)d_in[0];
    const float* k      = (const float*)d_in[1];
    const float* v      = (const float*)d_in[2];
    const float* ln_g   = (const float*)d_in[3];
    const float* ln_b   = (const float*)d_in[4];
    const float* w_in   = (const float*)d_in[5];
    const float* wp_w1  = (const float*)d_in[6];
    const float* wp_b1  = (const float*)d_in[7];
    const float* wp_lng = (const float*)d_in[8];
    const float* wp_lnb = (const float*)d_in[9];
    const float* wp_w2  = (const float*)d_in[10];
    const float* wp_b2  = (const float*)d_in[11];
    const float* w_out  = (const float*)d_in[12];
    const float* b_out  = (const float*)d_in[13];
    float* out = (float*)d_out;

    constexpr size_t F = (size_t)R * DIM;     // 8,388,608 elements
    u16* lnall   = (u16*)d_ws;                // 3F (LN out; first F reused as attn out)
    u16* fqb     = lnall + 3 * F;             // f_q row-major bf16
    u16* qT      = fqb + F;                   // [h][d][r]
    u16* kTh     = qT + F;                    // K/||k||
    u16* vT      = kTh + F;                   // V (plain)
    u16* w_in16  = vT + F;
    u16* w_out16 = w_in16 + (size_t)DIM * DIM;
    u16* Mt      = w_out16 + (size_t)DIM * DIM;   // H*QB*D*D = 2,097,152
    float* P     = (float*)(Mt + (size_t)H * QB * D * D);  // 16*H*D*D fp32
    float* fc    = P + (size_t)16 * H * D * D;
    float* qn    = fc + (size_t)H * D * D;
    float* qm    = qn + (size_t)H * R;
    float* qr    = qm + (size_t)H * R;
    float* kn    = qr + (size_t)H * R;
    float* kr    = kn + (size_t)H * R;
    float* qg    = kr + (size_t)H * R;        // H*D
    float* kg    = qg + H * D;
    float* ubuf  = kg + H * D;
    float* s2    = ubuf + H * D;              // H
    float* coef  = s2 + H;                    // 16
    float* svb   = coef + 16;                 // H*QB*D

    cvt2_kernel<<<2048, 256, 0, stream>>>(w_in, w_out, w_in16, w_out16, DIM * DIM / 4);
    ln_all<<<dim3(R, 3), 256, 0, stream>>>(q, k, v, ln_g, ln_b, lnall);

    gemm_qkv<<<dim3(DIM / 128, 3 * R / 128), 256, 0, stream>>>(
        lnall, w_in16, qT, fqb, kTh, vT, qn, qm, qr, kn, kr);

    colsum_b<1><<<dim3(16, H), 256, 0, stream>>>(qT, qm, qg, ubuf, s2);
    colsum_b<2><<<dim3(16, H), 256, 0, stream>>>(kTh, kn, kg, nullptr, nullptr);

    syrk_q<<<dim3(16, H), 256, 0, stream>>>(qT, P);
    reduce_fc<<<512, 256, 0, stream>>>(P, fc);

    head_kernel<<<H, 256, 0, stream>>>(fc, ubuf, s2, qg, kg, wp_w1, wp_b1,
                                       wp_lng, wp_lnb, wp_w2, wp_b2, coef);

    ktv_mfma<<<dim3(QB, H), 256, 0, stream>>>(kTh, vT, kr, Mt, svb);

    attn_mfma<<<dim3(4, QB, H), 256, 0, stream>>>(fqb, Mt, qn, qr, svb, coef, lnall);

    gemm_out<<<dim3(DIM / 128, R / 128), 256, 0, stream>>>(lnall, w_out16, b_out, out);
}

// Round 5
// 345.759 us; speedup vs baseline: 4.1529x; 1.1326x over previous
//
#include <hip/hip_runtime.h>
#include <hip/hip_bf16.h>

typedef unsigned short u16;
typedef __attribute__((ext_vector_type(8))) short short8;
typedef __attribute__((ext_vector_type(4))) float floatx4;

#define H 8
#define D 128
#define DIM 1024
#define QB 16
#define NSEQ 512
#define R 8192            /* QB*NSEQ rows */

__device__ inline u16 f2b(float x) {
    union { float f; unsigned int u; } c{x};
    unsigned int lsb = (c.u >> 16) & 1;
    unsigned int r = c.u + 0x7fffu + lsb;   // round-to-nearest-even
    return (u16)(r >> 16);
}
__device__ inline float b2f(u16 u) {
    union { unsigned int i; float f; } c;
    c.i = (unsigned int)u << 16;
    return c.f;
}

#define GLOAD_LDS16(gptr, lptr)                                                        \
    __builtin_amdgcn_global_load_lds(                                                  \
        (const __attribute__((address_space(1))) unsigned int*)(gptr),                 \
        (__attribute__((address_space(3))) unsigned int*)(lptr), 16, 0, 0)

// ---------------------------------------------------------------------------
// LayerNorm over DIM=1024 for q/k/v stacked: grid (R, 3) -> lnall[3R][DIM]
// ---------------------------------------------------------------------------
__global__ __launch_bounds__(256) void ln_all(const float* __restrict__ q,
                                              const float* __restrict__ k,
                                              const float* __restrict__ v,
                                              const float* __restrict__ g,
                                              const float* __restrict__ b,
                                              u16* __restrict__ out) {
    const float* src = (blockIdx.y == 0) ? q : (blockIdx.y == 1) ? k : v;
    int r = blockIdx.x;
    int tid = threadIdx.x;
    const float* row = src + (size_t)r * DIM;
    float4 vv = *(const float4*)(row + tid * 4);
    float sum = vv.x + vv.y + vv.z + vv.w;
    float sq = vv.x * vv.x + vv.y * vv.y + vv.z * vv.z + vv.w * vv.w;
    __shared__ float s1[256], s2[256];
    s1[tid] = sum; s2[tid] = sq;
    __syncthreads();
    for (int s = 128; s > 0; s >>= 1) {
        if (tid < s) { s1[tid] += s1[tid + s]; s2[tid] += s2[tid + s]; }
        __syncthreads();
    }
    float mean = s1[0] * (1.0f / DIM);
    float var = s2[0] * (1.0f / DIM) - mean * mean;
    float rstd = rsqrtf(var + 1e-5f);
    float4 gv = *(const float4*)(g + tid * 4);
    float4 bv = *(const float4*)(b + tid * 4);
    ushort4 pk;
    pk.x = f2b((vv.x - mean) * rstd * gv.x + bv.x);
    pk.y = f2b((vv.y - mean) * rstd * gv.y + bv.y);
    pk.z = f2b((vv.z - mean) * rstd * gv.z + bv.z);
    pk.w = f2b((vv.w - mean) * rstd * gv.w + bv.w);
    *(ushort4*)(out + ((size_t)blockIdx.y * R + r) * DIM + tid * 4) = pk;
}

// ---------------------------------------------------------------------------
__global__ __launch_bounds__(256) void cvt2_kernel(const float* __restrict__ a,
                                                   const float* __restrict__ b,
                                                   u16* __restrict__ oa,
                                                   u16* __restrict__ ob, int n4each) {
    int i = blockIdx.x * 256 + threadIdx.x;
    const float* src; u16* dst; int j;
    if (i < n4each) { src = a; dst = oa; j = i; }
    else            { src = b; dst = ob; j = i - n4each; }
    float4 v = *(const float4*)(src + (size_t)j * 4);
    ushort4 pk;
    pk.x = f2b(v.x); pk.y = f2b(v.y); pk.z = f2b(v.z); pk.w = f2b(v.w);
    *(ushort4*)(dst + (size_t)j * 4) = pk;
}

// ---------------------------------------------------------------------------
// Stacked QKV projection, operand-SWAPPED MFMA (acc: fr = data row r,
// kq*4+reg = feature col c) so transposed stores are 32B-contiguous.
// 1-D grid 1536, XCD swizzle: xcd=b&7 gets 24 row-blocks x 8 cols, cols
// innermost -> A-tile L2 reuse within XCD.
// seg 0=Q (qT + fqb via LDS transpose + qn/qm/qr), 1=K (kTh=K/||k||, kn/kr),
// 2=V (vT plain).
// ---------------------------------------------------------------------------
__global__ __launch_bounds__(256) void gemm_qkv(const u16* __restrict__ A,
                                                const u16* __restrict__ B,
                                                u16* __restrict__ qT,
                                                u16* __restrict__ fqb,
                                                u16* __restrict__ kTh,
                                                u16* __restrict__ vT,
                                                float* __restrict__ qn,
                                                float* __restrict__ qm,
                                                float* __restrict__ qr,
                                                float* __restrict__ kn,
                                                float* __restrict__ kr) {
    __shared__ u16 smem[19712];
    u16* As = smem;                              // 4096 u16
    u16* Bs = smem + 4096;                       // 4096 u16
    float* sred = (float*)(smem + 18432);        // 128*4 floats
    float* invb = (float*)(smem + 19456);        // 128 floats

    const int tid = threadIdx.x;
    const int bb = blockIdx.x;
    const int xcd = bb & 7, j0 = bb >> 3;
    const int h = j0 & 7;                        // column block (head)
    const int rowblk = xcd * 24 + (j0 >> 3);     // 0..191
    const int m0 = rowblk * 128, n0 = h * 128;
    const int seg = rowblk >> 6;                 // 0=Q 1=K 2=V
    const int lrb = (rowblk & 63) * 128;         // segment-local row base

    const int wave = tid >> 6, lane = tid & 63;
    const int wm = (wave >> 1) * 64, wn = (wave & 1) * 64;
    const int fr = lane & 15, kq = lane >> 4;
    const int srow = tid >> 2, scol = (tid & 3) * 8;

    floatx4 acc[4][4] = {};                      // [j=c-tile][i=r-tile]
    const size_t aOff0 = (size_t)(m0 + srow) * DIM + scol;
    const size_t aOff1 = (size_t)(m0 + 64 + srow) * DIM + scol;
    const size_t bOff0 = (size_t)(n0 + srow) * DIM + scol;
    const size_t bOff1 = (size_t)(n0 + 64 + srow) * DIM + scol;

    for (int kt = 0; kt < DIM; kt += 32) {
        GLOAD_LDS16(A + aOff0 + kt, As + tid * 8);
        GLOAD_LDS16(A + aOff1 + kt, As + (256 + tid) * 8);
        GLOAD_LDS16(B + bOff0 + kt, Bs + tid * 8);
        GLOAD_LDS16(B + bOff1 + kt, Bs + (256 + tid) * 8);
        __syncthreads();
        short8 xf[4], wf[4];
#pragma unroll
        for (int i = 0; i < 4; i++)
            xf[i] = *(const short8*)&As[(wm + i * 16 + fr) * 32 + kq * 8];
#pragma unroll
        for (int j = 0; j < 4; j++)
            wf[j] = *(const short8*)&Bs[(wn + j * 16 + fr) * 32 + kq * 8];
#pragma unroll
        for (int j = 0; j < 4; j++)
#pragma unroll
            for (int i = 0; i < 4; i++)
                acc[j][i] = __builtin_amdgcn_mfma_f32_16x16x32_bf16(wf[j], xf[i], acc[j][i], 0, 0, 0);
        __syncthreads();
    }

    // ---- per-row stats: lane holds rows r = wm+i*16+fr, cols c = wn+j*16+kq*4+reg
    if (seg <= 1) {
        const int half = wn >> 6;
#pragma unroll
        for (int i = 0; i < 4; i++) {
            float s = 0.0f, qs = 0.0f;
#pragma unroll
            for (int j = 0; j < 4; j++)
#pragma unroll
                for (int rg = 0; rg < 4; rg++) {
                    float vv = acc[j][i][rg];
                    s += vv; qs += vv * vv;
                }
            s += __shfl_xor(s, 16); qs += __shfl_xor(qs, 16);
            s += __shfl_xor(s, 32); qs += __shfl_xor(qs, 32);
            if (kq == 0) {
                int rl = wm + i * 16 + fr;
                sred[rl * 4 + half * 2 + 0] = s;
                sred[rl * 4 + half * 2 + 1] = qs;
            }
        }
        __syncthreads();
        if (tid < 128) {
            float sum = sred[tid * 4 + 0] + sred[tid * 4 + 2];
            float sq  = sred[tid * 4 + 1] + sred[tid * 4 + 3];
            float nrm = sqrtf(sq);
            float var = (sq - sum * sum * (1.0f / D)) * (1.0f / (D - 1));
            float ratio = 2.0f * fminf(var, 1.0f) / (var + 1.0f);
            size_t idx = (size_t)h * R + lrb + tid;
            if (seg == 0) {
                qn[idx] = nrm; qm[idx] = sum * (1.0f / D); qr[idx] = ratio;
            } else {
                kn[idx] = nrm; kr[idx] = ratio;
                invb[tid] = 1.0f / nrm;
            }
        }
        __syncthreads();
    }

    // ---- transposed store: qT/kTh/vT [h][c][r] -- 16-lane r-contiguous
    u16* dstT = (seg == 0) ? qT : (seg == 1) ? kTh : vT;
#pragma unroll
    for (int i = 0; i < 4; i++) {
        const int rl = wm + i * 16 + fr;
        const float sc = (seg == 1) ? invb[rl] : 1.0f;
#pragma unroll
        for (int j = 0; j < 4; j++) {
#pragma unroll
            for (int rg = 0; rg < 4; rg++) {
                const int cl = wn + j * 16 + kq * 4 + rg;
                dstT[(size_t)(h * D + cl) * R + lrb + rl] = f2b(acc[j][i][rg] * sc);
            }
        }
    }

    // ---- seg 0: fqb row-major via padded LDS transpose (coalesced 128B rows)
    if (seg == 0) {
        __syncthreads();
        u16* Tw = smem + wave * 4608;            // 64 x 72 u16
#pragma unroll
        for (int i = 0; i < 4; i++)
#pragma unroll
            for (int j = 0; j < 4; j++) {
                ushort4 pk;
                pk.x = f2b(acc[j][i][0]); pk.y = f2b(acc[j][i][1]);
                pk.z = f2b(acc[j][i][2]); pk.w = f2b(acc[j][i][3]);
                *(ushort4*)&Tw[(i * 16 + fr) * 72 + j * 16 + kq * 4] = pk;
            }
        __syncthreads();
#pragma unroll
        for (int p = 0; p < 16; p++) {
            int rloc = p * 4 + kq;
            int c4 = fr * 4;
            ushort4 v = *(const ushort4*)&Tw[rloc * 72 + c4];
            *(ushort4*)&fqb[(size_t)(lrb + wm + rloc) * DIM + h * D + wn + c4] = v;
        }
    }
}

// ---------------------------------------------------------------------------
// Combined column reductions from [h][d][r]; blockIdx.z: 0=Q 1=K.
// Q: qg=colmean, ubuf=sum qm*f, s2[h]=sum qm^2.  K: kg=(1/R) sum khat*kn.
// ---------------------------------------------------------------------------
__global__ __launch_bounds__(256) void colsum2(const u16* __restrict__ qT,
                                               const u16* __restrict__ kTh,
                                               const float* __restrict__ qm,
                                               const float* __restrict__ kn,
                                               float* __restrict__ qg,
                                               float* __restrict__ kg,
                                               float* __restrict__ ubuf,
                                               float* __restrict__ s2) {
    int dg = blockIdx.x, h = blockIdx.y, mode = blockIdx.z, tid = threadIdx.x;
    const u16* fT = mode ? kTh : qT;
    const float* wvec = mode ? kn : qm;
    __shared__ float r1[256], r2[256];
    for (int dd = 0; dd < 8; dd++) {
        int d = dg * 8 + dd;
        const u16* rowp = fT + (size_t)(h * D + d) * R;
        float s = 0.0f, su = 0.0f;
        for (int it = 0; it < 32; it++) {
            int r = it * 256 + tid;
            float v = b2f(rowp[r]);
            float w = wvec[h * R + r];
            if (mode) s += v * w;
            else { s += v; su += v * w; }
        }
        r1[tid] = s; r2[tid] = su;
        __syncthreads();
        for (int st = 128; st > 0; st >>= 1) {
            if (tid < st) { r1[tid] += r1[tid + st]; r2[tid] += r2[tid + st]; }
            __syncthreads();
        }
        if (tid == 0) {
            if (mode) kg[h * D + d] = r1[0] * (1.0f / R);
            else { qg[h * D + d] = r1[0] * (1.0f / R); ubuf[h * D + d] = r2[0]; }
        }
        __syncthreads();
    }
    if (!mode && dg == 0) {
        float t = 0.0f;
        for (int it = 0; it < 32; it++) {
            float m = qm[h * R + it * 256 + tid];
            t += m * m;
        }
        r1[tid] = t;
        __syncthreads();
        for (int st = 128; st > 0; st >>= 1) {
            if (tid < st) r1[tid] += r1[tid + st];
            __syncthreads();
        }
        if (tid == 0) s2[h] = r1[0];
    }
}

// ---------------------------------------------------------------------------
// Raw syrk partials, 32 K-chunks of 256: P[h][c][d][e]
// ---------------------------------------------------------------------------
__global__ __launch_bounds__(256) void syrk_q(const u16* __restrict__ qT,
                                              float* __restrict__ P) {
    __shared__ u16 As[128 * 32];
    const int c = blockIdx.x, h = blockIdx.y;
    const int tid = threadIdx.x;
    const int wave = tid >> 6, lane = tid & 63;
    const int wm = (wave >> 1) * 64, wn = (wave & 1) * 64;
    const int fr = lane & 15, kq = lane >> 4;
    const int srow = tid >> 2, scol = (tid & 3) * 8;
    floatx4 acc[4][4] = {};
    const size_t a0 = (size_t)(h * D + srow) * R + c * 256 + scol;
    const size_t a1 = (size_t)(h * D + 64 + srow) * R + c * 256 + scol;
    for (int kt = 0; kt < 256; kt += 32) {
        GLOAD_LDS16(qT + a0 + kt, As + tid * 8);
        GLOAD_LDS16(qT + a1 + kt, As + (256 + tid) * 8);
        __syncthreads();
        short8 af[4], bf[4];
#pragma unroll
        for (int i = 0; i < 4; i++)
            af[i] = *(const short8*)&As[(wm + i * 16 + fr) * 32 + kq * 8];
#pragma unroll
        for (int j = 0; j < 4; j++)
            bf[j] = *(const short8*)&As[(wn + j * 16 + fr) * 32 + kq * 8];
#pragma unroll
        for (int i = 0; i < 4; i++)
#pragma unroll
            for (int j = 0; j < 4; j++)
                acc[i][j] = __builtin_amdgcn_mfma_f32_16x16x32_bf16(af[i], bf[j], acc[i][j], 0, 0, 0);
        __syncthreads();
    }
    float* base = P + (size_t)(h * 32 + c) * (D * D);
#pragma unroll
    for (int i = 0; i < 4; i++) {
        int dr = wm + i * 16 + kq * 4;
#pragma unroll
        for (int j = 0; j < 4; j++) {
            int ec = wn + j * 16 + fr;
#pragma unroll
            for (int r = 0; r < 4; r++)
                base[(size_t)(dr + r) * D + ec] = acc[i][j][r];
        }
    }
}

// ---------------------------------------------------------------------------
// Reduce syrk partials + centering + off-diag Frobenius partial per block.
// grid (8, H): Spart[h*8 + bx] (deterministic, no atomics)
// ---------------------------------------------------------------------------
__global__ __launch_bounds__(256) void decorr_sum(const float* __restrict__ P,
                                                  const float* __restrict__ ubuf,
                                                  const float* __restrict__ s2b,
                                                  float* __restrict__ Spart) {
    int bx = blockIdx.x, h = blockIdx.y, tid = threadIdx.x;
    float s2h = s2b[h];
    float S = 0.0f;
    for (int t = 0; t < 8; t++) {
        int de = bx * 2048 + t * 256 + tid;
        int dd = de >> 7, ee = de & 127;
        float g = 0.0f;
        for (int c = 0; c < 32; c++)
            g += P[(size_t)(h * 32 + c) * (D * D) + de];
        if (dd != ee) {
            float vv = (g - ubuf[h * D + dd] - ubuf[h * D + ee] + s2h) * (1.0f / R);
            S += vv * vv;
        }
    }
    __shared__ float r1[256];
    r1[tid] = S;
    __syncthreads();
    for (int st = 128; st > 0; st >>= 1) {
        if (tid < st) r1[tid] += r1[tid + st];
        __syncthreads();
    }
    if (tid == 0) Spart[h * 8 + bx] = r1[0];
}

// ---------------------------------------------------------------------------
// Per-head: dscale from Spart + predictor MLP -> coef
// ---------------------------------------------------------------------------
__global__ __launch_bounds__(256) void head_kernel(const float* __restrict__ Spart,
                                                   const float* __restrict__ qg,
                                                   const float* __restrict__ kg,
                                                   const float* __restrict__ w1,
                                                   const float* __restrict__ b1,
                                                   const float* __restrict__ lng,
                                                   const float* __restrict__ lnb,
                                                   const float* __restrict__ w2,
                                                   const float* __restrict__ b2,
                                                   float* __restrict__ coef) {
    int h = blockIdx.x, tid = threadIdx.x;
    __shared__ float s1[256], s2[256], s3[256];
    __shared__ float feats[256];
    float Ssum = 0.0f;
    for (int c = 0; c < 8; c++) Ssum += Spart[h * 8 + c];
    float dscale = expf(-5.0f * sqrtf(Ssum) / (float)(D * D));
    feats[tid] = (tid < 128) ? qg[h * D + tid] : kg[h * D + tid - 128];
    __syncthreads();
    float yv = 0.0f;
    if (tid < 128) {
        float a = b1[tid];
        for (int i = 0; i < 256; i++) a = fmaf(feats[i], w1[tid * 256 + i], a);
        yv = a;
    }
    s1[tid] = (tid < 128) ? yv : 0.0f;
    s2[tid] = (tid < 128) ? yv * yv : 0.0f;
    __syncthreads();
    for (int s = 128; s > 0; s >>= 1) {
        if (tid < s) { s1[tid] += s1[tid + s]; s2[tid] += s2[tid + s]; }
        __syncthreads();
    }
    float mean = s1[0] * (1.0f / 128.0f);
    float var = s2[0] * (1.0f / 128.0f) - mean * mean;
    float rstd = rsqrtf(var + 1e-5f);
    float rel = 0.0f;
    if (tid < 128)
        rel = fmaxf((yv - mean) * rstd * lng[tid] + lnb[tid], 0.0f);
    __syncthreads();
    s1[tid] = (tid < 128) ? rel * w2[0 * 128 + tid] : 0.0f;
    s2[tid] = (tid < 128) ? rel * w2[1 * 128 + tid] : 0.0f;
    s3[tid] = (tid < 128) ? rel * w2[2 * 128 + tid] : 0.0f;
    __syncthreads();
    for (int s = 128; s > 0; s >>= 1) {
        if (tid < s) { s1[tid] += s1[tid + s]; s2[tid] += s2[tid + s]; s3[tid] += s3[tid + s]; }
        __syncthreads();
    }
    if (tid == 0) {
        float g0 = s1[0] + b2[0], g1 = s2[0] + b2[1], g2 = s3[0] + b2[2];
        float mx = fmaxf(g0, fmaxf(g1, g2));
        float e0 = expf(g0 - mx), e1 = expf(g1 - mx), e2 = expf(g2 - mx);
        float inv = 1.0f / (e0 + e1 + e2);
        coef[h * 2 + 0] = e0 * inv + e1 * inv * dscale;  // cw + vw*decorr_scale
        coef[h * 2 + 1] = e2 * inv;                      // ww
    }
}

// ---------------------------------------------------------------------------
// Mt[h][qi][e][d] = sum_m V[m,e] * Khat[m,d]; sv folded in staging loop.
// ---------------------------------------------------------------------------
__global__ __launch_bounds__(256) void ktv_mfma(const u16* __restrict__ kTh,
                                                const u16* __restrict__ vT,
                                                const float* __restrict__ kr,
                                                u16* __restrict__ Mt,
                                                float* __restrict__ sv) {
    __shared__ u16 As[128 * 32];
    __shared__ u16 Bs[128 * 32];
    __shared__ float wbuf[32];
    __shared__ float svred[256];
    const int qi = blockIdx.x, h = blockIdx.y;
    const int tid = threadIdx.x;
    const int wave = tid >> 6, lane = tid & 63;
    const int wm = (wave >> 1) * 64, wn = (wave & 1) * 64;
    const int fr = lane & 15, kq = lane >> 4;
    const int srow = tid >> 2, scol = (tid & 3) * 8;
    const int m0g = qi * 512;
    const size_t a0 = (size_t)(h * D + srow) * R + m0g + scol;
    const size_t a1 = (size_t)(h * D + 64 + srow) * R + m0g + scol;
    const int e_id = tid & 127, eh = tid >> 7;
    float svacc = 0.0f;
    floatx4 acc[4][4] = {};
    for (int kt = 0; kt < 512; kt += 32) {
        GLOAD_LDS16(vT + a0 + kt, As + tid * 8);
        GLOAD_LDS16(vT + a1 + kt, As + (256 + tid) * 8);
        GLOAD_LDS16(kTh + a0 + kt, Bs + tid * 8);
        GLOAD_LDS16(kTh + a1 + kt, Bs + (256 + tid) * 8);
        if (tid < 32) wbuf[tid] = kr[(size_t)h * R + m0g + kt + tid];
        __syncthreads();
        short8 af[4], bf[4];
#pragma unroll
        for (int i = 0; i < 4; i++)
            af[i] = *(const short8*)&As[(wm + i * 16 + fr) * 32 + kq * 8];
#pragma unroll
        for (int j = 0; j < 4; j++)
            bf[j] = *(const short8*)&Bs[(wn + j * 16 + fr) * 32 + kq * 8];
#pragma unroll
        for (int i = 0; i < 4; i++)
#pragma unroll
            for (int j = 0; j < 4; j++)
                acc[i][j] = __builtin_amdgcn_mfma_f32_16x16x32_bf16(af[i], bf[j], acc[i][j], 0, 0, 0);
#pragma unroll
        for (int jm = 0; jm < 16; jm++) {
            int mm = eh * 16 + jm;
            svacc += b2f(As[e_id * 32 + mm]) * wbuf[mm];
        }
        __syncthreads();
    }
    u16* mb = Mt + (size_t)(h * QB + qi) * D * D;
#pragma unroll
    for (int i = 0; i < 4; i++) {
        int er = wm + i * 16 + kq * 4;
#pragma unroll
        for (int j = 0; j < 4; j++) {
            int dc = wn + j * 16 + fr;
#pragma unroll
            for (int r = 0; r < 4; r++)
                mb[(size_t)(er + r) * D + dc] = f2b(acc[i][j][r]);
        }
    }
    svred[tid] = svacc;
    __syncthreads();
    if (tid < 128)
        sv[(size_t)(h * QB + qi) * D + tid] = svred[tid] + svred[tid + 128];
}

// ---------------------------------------------------------------------------
// attn: out[n,e] = sc1[n]*(sum_d fq[n,d]*Mt[e,d]) + sc2[n]*sv[e]  -> bf16
// ---------------------------------------------------------------------------
__global__ __launch_bounds__(256) void attn_mfma(const u16* __restrict__ fqb,
                                                 const u16* __restrict__ Mt,
                                                 const float* __restrict__ qn,
                                                 const float* __restrict__ qr,
                                                 const float* __restrict__ sv,
                                                 const float* __restrict__ coef,
                                                 u16* __restrict__ outb) {
    __shared__ u16 As[128 * 32];
    __shared__ u16 Bs[128 * 32];
    const int nb = blockIdx.x, qi = blockIdx.y, h = blockIdx.z;
    const int tid = threadIdx.x;
    const int wave = tid >> 6, lane = tid & 63;
    const int wm = (wave >> 1) * 64, wn = (wave & 1) * 64;
    const int fr = lane & 15, kq = lane >> 4;
    const int srow = tid >> 2, scol = (tid & 3) * 8;
    const int n0g = qi * 512 + nb * 128;
    const size_t a0 = (size_t)(n0g + srow) * DIM + h * D + scol;
    const size_t a1 = (size_t)(n0g + 64 + srow) * DIM + h * D + scol;
    const u16* mtb = Mt + (size_t)(h * QB + qi) * D * D;
    floatx4 acc[4][4] = {};
    for (int kt = 0; kt < 128; kt += 32) {
        GLOAD_LDS16(fqb + a0 + kt, As + tid * 8);
        GLOAD_LDS16(fqb + a1 + kt, As + (256 + tid) * 8);
        GLOAD_LDS16(mtb + (size_t)srow * D + kt + scol, Bs + tid * 8);
        GLOAD_LDS16(mtb + (size_t)(64 + srow) * D + kt + scol, Bs + (256 + tid) * 8);
        __syncthreads();
        short8 af[4], bf[4];
#pragma unroll
        for (int i = 0; i < 4; i++)
            af[i] = *(const short8*)&As[(wm + i * 16 + fr) * 32 + kq * 8];
#pragma unroll
        for (int j = 0; j < 4; j++)
            bf[j] = *(const short8*)&Bs[(wn + j * 16 + fr) * 32 + kq * 8];
#pragma unroll
        for (int i = 0; i < 4; i++)
#pragma unroll
            for (int j = 0; j < 4; j++)
                acc[i][j] = __builtin_amdgcn_mfma_f32_16x16x32_bf16(af[i], bf[j], acc[i][j], 0, 0, 0);
        __syncthreads();
    }
    float c0 = coef[2 * h], c1 = coef[2 * h + 1];
#pragma unroll
    for (int i = 0; i < 4; i++) {
        int nr = n0g + wm + i * 16 + kq * 4;
        float sc1[4], sc2[4];
#pragma unroll
        for (int r = 0; r < 4; r++) {
            sc1[r] = c0 / qn[(size_t)h * R + nr + r];
            sc2[r] = c1 * qr[(size_t)h * R + nr + r];
        }
#pragma unroll
        for (int j = 0; j < 4; j++) {
            int ec = wn + j * 16 + fr;
            float svv = sv[(size_t)(h * QB + qi) * D + ec];
#pragma unroll
            for (int r = 0; r < 4; r++)
                outb[(size_t)(nr + r) * DIM + h * D + ec] = f2b(sc1[r] * acc[i][j][r] + sc2[r] * svv);
        }
    }
}

// ---------------------------------------------------------------------------
// Output GEMM, 1-D grid 512 with XCD swizzle (8 row-blocks x 8 cols / XCD)
// ---------------------------------------------------------------------------
__global__ __launch_bounds__(256) void gemm_out(const u16* __restrict__ A,
                                                const u16* __restrict__ B,
                                                const float* __restrict__ bias,
                                                float* __restrict__ C) {
    __shared__ u16 As[128 * 32];
    __shared__ u16 Bs[128 * 32];
    const int tid = threadIdx.x;
    const int bb = blockIdx.x;
    const int xcd = bb & 7, jj = bb >> 3;
    const int col = jj & 7, rowblk = xcd * 8 + (jj >> 3);
    const int m0 = rowblk * 128, n0 = col * 128;
    const int wave = tid >> 6, lane = tid & 63;
    const int wm = (wave >> 1) * 64, wn = (wave & 1) * 64;
    const int fr = lane & 15, kq = lane >> 4;
    const int srow = tid >> 2, scol = (tid & 3) * 8;
    floatx4 acc[4][4] = {};
    const size_t aOff0 = (size_t)(m0 + srow) * DIM + scol;
    const size_t aOff1 = (size_t)(m0 + 64 + srow) * DIM + scol;
    const size_t bOff0 = (size_t)(n0 + srow) * DIM + scol;
    const size_t bOff1 = (size_t)(n0 + 64 + srow) * DIM + scol;
    for (int kt = 0; kt < DIM; kt += 32) {
        GLOAD_LDS16(A + aOff0 + kt, As + tid * 8);
        GLOAD_LDS16(A + aOff1 + kt, As + (256 + tid) * 8);
        GLOAD_LDS16(B + bOff0 + kt, Bs + tid * 8);
        GLOAD_LDS16(B + bOff1 + kt, Bs + (256 + tid) * 8);
        __syncthreads();
        short8 af[4], bf[4];
#pragma unroll
        for (int i = 0; i < 4; i++)
            af[i] = *(const short8*)&As[(wm + i * 16 + fr) * 32 + kq * 8];
#pragma unroll
        for (int j = 0; j < 4; j++)
            bf[j] = *(const short8*)&Bs[(wn + j * 16 + fr) * 32 + kq * 8];
#pragma unroll
        for (int i = 0; i < 4; i++)
#pragma unroll
            for (int j = 0; j < 4; j++)
                acc[i][j] = __builtin_amdgcn_mfma_f32_16x16x32_bf16(af[i], bf[j], acc[i][j], 0, 0, 0);
        __syncthreads();
    }
#pragma unroll
    for (int i = 0; i < 4; i++) {
        int rbase = m0 + wm + i * 16 + kq * 4;
#pragma unroll
        for (int j = 0; j < 4; j++) {
            int c = n0 + wn + j * 16 + fr;
            float badd = bias[c];
#pragma unroll
            for (int r = 0; r < 4; r++)
                C[(size_t)(rbase + r) * DIM + c] = acc[i][j][r] + badd;
        }
    }
}

// ---------------------------------------------------------------------------
extern "C" void kernel_launch(void* const* d_in, const int* in_sizes, int n_in,
                              void* d_out, int out_size, void* d_ws, size_t ws_size,
                              hipStream_t stream) {
    (void)in_sizes; (void)n_in; (void)out_size; (void)ws_size;
    const float* q      = (const float*)d_in[0];
    const float* k      = (const float*)d_in[1];
    const float* v      = (const float*)d_in[2];
    const float* ln_g   = (const float*)d_in[3];
    const float* ln_b   = (const float*)d_in[4];
    const float* w_in   = (const float*)d_in[5];
    const float* wp_w1  = (const float*)d_in[6];
    const float* wp_b1  = (const float*)d_in[7];
    const float* wp_lng = (const float*)d_in[8];
    const float* wp_lnb = (const float*)d_in[9];
    const float* wp_w2  = (const float*)d_in[10];
    const float* wp_b2  = (const float*)d_in[11];
    const float* w_out  = (const float*)d_in[12];
    const float* b_out  = (const float*)d_in[13];
    float* out = (float*)d_out;

    constexpr size_t F = (size_t)R * DIM;     // 8,388,608 elements
    u16* lnall   = (u16*)d_ws;                // 3F (LN out; first F reused as attn out)
    u16* fqb     = lnall + 3 * F;             // f_q row-major bf16
    u16* qT      = fqb + F;                   // [h][d][r]
    u16* kTh     = qT + F;                    // K/||k||
    u16* vT      = kTh + F;                   // V (plain)
    u16* w_in16  = vT + F;
    u16* w_out16 = w_in16 + (size_t)DIM * DIM;
    u16* Mt      = w_out16 + (size_t)DIM * DIM;       // H*QB*D*D
    float* P     = (float*)(Mt + (size_t)H * QB * D * D);  // 32*H*D*D fp32
    float* qn    = P + (size_t)32 * H * D * D;
    float* qm    = qn + (size_t)H * R;
    float* qr    = qm + (size_t)H * R;
    float* kn    = qr + (size_t)H * R;
    float* kr    = kn + (size_t)H * R;
    float* qg    = kr + (size_t)H * R;        // H*D
    float* kg    = qg + H * D;
    float* ubuf  = kg + H * D;
    float* s2    = ubuf + H * D;              // H
    float* Spart = s2 + H;                    // H*8
    float* coef  = Spart + H * 8;             // 16
    float* svb   = coef + 16;                 // H*QB*D

    cvt2_kernel<<<2048, 256, 0, stream>>>(w_in, w_out, w_in16, w_out16, DIM * DIM / 4);
    ln_all<<<dim3(R, 3), 256, 0, stream>>>(q, k, v, ln_g, ln_b, lnall);

    gemm_qkv<<<1536, 256, 0, stream>>>(lnall, w_in16, qT, fqb, kTh, vT,
                                       qn, qm, qr, kn, kr);

    colsum2<<<dim3(16, H, 2), 256, 0, stream>>>(qT, kTh, qm, kn, qg, kg, ubuf, s2);

    syrk_q<<<dim3(32, H), 256, 0, stream>>>(qT, P);
    decorr_sum<<<dim3(8, H), 256, 0, stream>>>(P, ubuf, s2, Spart);

    head_kernel<<<H, 256, 0, stream>>>(Spart, qg, kg, wp_w1, wp_b1,
                                       wp_lng, wp_lnb, wp_w2, wp_b2, coef);

    ktv_mfma<<<dim3(QB, H), 256, 0, stream>>>(kTh, vT, kr, Mt, svb);

    attn_mfma<<<dim3(4, QB, H), 256, 0, stream>>>(fqb, Mt, qn, qr, svb, coef, lnall);

    gemm_out<<<512, 256, 0, stream>>>(lnall, w_out16, b_out, out);
}